// Round 16
// baseline (273.305 us; speedup 1.0000x reference)
//
#include <hip/hip_runtime.h>

#define NTOK 8192

typedef __attribute__((ext_vector_type(8))) short short8;
typedef __attribute__((ext_vector_type(4))) float f32x4;

__device__ __forceinline__ unsigned short f2bf(float f) {
  unsigned u = __float_as_uint(f);
  u += 0x7FFFu + ((u >> 16) & 1u);
  return (unsigned short)(u >> 16);
}
__device__ __forceinline__ float bf2f(unsigned short u) {
  return __uint_as_float(((unsigned)u) << 16);
}

// ---------------- fused patchify + gate: one block per token ---------------
__global__ __launch_bounds__(256) void patchgate_kernel(
    const float* __restrict__ x, const float* __restrict__ gw,
    const float* __restrict__ gb, unsigned short* __restrict__ flatbf,
    int* __restrict__ gidx, float* __restrict__ gval,
    float* __restrict__ probs)
{
  int t = blockIdx.x;          // 0..8191
  int tid = threadIdx.x;
  int b = t >> 8, ph = (t >> 4) & 15, pw = t & 15;
  const float* xb = x + (size_t)b * 3 * 256 * 256;
  float acc[8];
  #pragma unroll
  for (int e = 0; e < 8; ++e) acc[e] = 0.f;
  #pragma unroll
  for (int r = 0; r < 3; ++r) {
    int d = r * 256 + tid;
    int c = d >> 8, i = (d >> 4) & 15, j = d & 15;
    float v = xb[((size_t)c * 256 + ph * 16 + i) * 256 + pw * 16 + j];
    flatbf[(size_t)t * 768 + d] = f2bf(v);
    const float* g = gw + d * 8;
    #pragma unroll
    for (int e = 0; e < 8; ++e) acc[e] += v * g[e];
  }
  #pragma unroll
  for (int e = 0; e < 8; ++e) {
    #pragma unroll
    for (int off = 32; off > 0; off >>= 1)
      acc[e] += __shfl_down(acc[e], off, 64);
  }
  __shared__ float s_red[4][8];
  int wid = tid >> 6, lane = tid & 63;
  if (lane == 0) {
    #pragma unroll
    for (int e = 0; e < 8; ++e) s_red[wid][e] = acc[e];
  }
  __syncthreads();
  if (tid == 0) {
    float lg[8];
    #pragma unroll
    for (int e = 0; e < 8; ++e)
      lg[e] = s_red[0][e] + s_red[1][e] + s_red[2][e] + s_red[3][e] + gb[e];
    int i0 = 0; float v0 = lg[0];
    #pragma unroll
    for (int e = 1; e < 8; ++e) if (lg[e] > v0) { v0 = lg[e]; i0 = e; }
    int i1 = -1; float v1 = -1e30f;
    #pragma unroll
    for (int e = 0; e < 8; ++e) { if (e == i0) continue; if (lg[e] > v1) { v1 = lg[e]; i1 = e; } }
    float e1 = __expf(v1 - v0);
    float s0 = 1.f / (1.f + e1);
    float s1 = e1 * s0;
    gidx[t * 2] = i0; gidx[t * 2 + 1] = i1;
    gval[t * 2] = s0; gval[t * 2 + 1] = s1;
    float sum = 0.f, p[8];
    #pragma unroll
    for (int e = 0; e < 8; ++e) { p[e] = __expf(lg[e] - v0); sum += p[e]; }
    float inv = 1.f / sum;
    #pragma unroll
    for (int e = 0; e < 8; ++e) probs[t * 8 + e] = p[e] * inv;
  }
}

// ---------------- aux reduction: me from probs, ce from gidx ---------------
__global__ __launch_bounds__(256) void auxred_kernel(const float* __restrict__ probs,
                                                     const int* __restrict__ gidx,
                                                     float* __restrict__ aux)
{
  __shared__ float s_me[8];
  __shared__ float s_ce[8];
  int tid = threadIdx.x, lane = tid & 63;
  if (tid < 8) { s_me[tid] = 0.f; s_ce[tid] = 0.f; }
  __syncthreads();
  int t = blockIdx.x * 256 + tid;
  float p[8];
  #pragma unroll
  for (int e = 0; e < 8; ++e) p[e] = probs[t * 8 + e];
  int top1 = gidx[t * 2];
  #pragma unroll
  for (int e = 0; e < 8; ++e) {
    #pragma unroll
    for (int off = 32; off > 0; off >>= 1)
      p[e] += __shfl_down(p[e], off, 64);
  }
  if (lane == 0) {
    #pragma unroll
    for (int e = 0; e < 8; ++e) atomicAdd(&s_me[e], p[e]);
  }
  #pragma unroll
  for (int e = 0; e < 8; ++e) {
    unsigned long long m = __ballot(top1 == e);
    if (lane == 0) atomicAdd(&s_ce[e], (float)__popcll(m));
  }
  __syncthreads();
  if (tid < 8) {
    atomicAdd(&aux[tid * 16], s_ce[tid]);            // ce
    atomicAdd(&aux[128 + tid * 16], s_me[tid]);      // me
  }
}

// ---------------- bin token-slots by expert --------------------------------
__global__ __launch_bounds__(256) void bin_kernel(const int* __restrict__ gidx,
                                                  int* __restrict__ cnt,
                                                  int* __restrict__ bin)
{
  int idx = blockIdx.x * 256 + threadIdx.x;   // 0..16383 (t*2+slot)
  int e = gidx[idx];
  int pos = atomicAdd(&cnt[e], 1);
  bin[e * 8192 + pos] = idx;
}

// ---------------- l_aux finalize -------------------------------------------
__global__ void laux_kernel(const float* __restrict__ aux, float* __restrict__ out)
{
  if (threadIdx.x == 0 && blockIdx.x == 0) {
    float l = 0.f;
    for (int e = 0; e < 8; ++e)
      l += (aux[e * 16] / 8192.f) * (aux[128 + e * 16] / 8192.f);
    out[2097152] = 8.f * l;
  }
}

// ---------------- fp32 -> bf16 convert of pw2w/pw3w/tew in one launch ------
__global__ __launch_bounds__(256) void f2bf3_kernel(const float* __restrict__ a,
                                                    const float* __restrict__ b,
                                                    const float* __restrict__ c,
                                                    unsigned short* __restrict__ oa,
                                                    unsigned short* __restrict__ ob,
                                                    unsigned short* __restrict__ oc)
{
  int blk = blockIdx.x;
  const float* in; unsigned short* out; size_t base;
  if (blk < 64)       { in = a; out = oa; base = (size_t)blk * 1024; }
  else if (blk < 320) { in = b; out = ob; base = (size_t)(blk - 64) * 1024; }
  else                { in = c; out = oc; base = (size_t)(blk - 320) * 1024; }
  size_t i = base + threadIdx.x * 4;
  float4 v = *reinterpret_cast<const float4*>(in + i);
  ushort4 o;
  o.x = f2bf(v.x); o.y = f2bf(v.y); o.z = f2bf(v.z); o.w = f2bf(v.w);
  *reinterpret_cast<ushort4*>(out + i) = o;
}

// ---------------- Wfused[e][o][k] = sum_d te[o,d] * M_e[d,k] ---------------
__global__ __launch_bounds__(256) void wfuse_kernel(const unsigned short* __restrict__ tebf, // [256][768]
                                                    const float* __restrict__ resw,
                                                    const float* __restrict__ thw,
                                                    unsigned short* __restrict__ Wf)
{
  int kt = blockIdx.x, oq = blockIdx.y, e = blockIdx.z;
  const float* src; int ld, kcol0;
  if (kt < 12) { src = resw + (size_t)e * 768 * 768; ld = 768; kcol0 = kt * 64; }
  else         { src = thw + (size_t)e * 768 * 256;  ld = 256; kcol0 = (kt - 12) * 64; }

  __shared__ unsigned short s_t[64 * 64];  // [k][d] XOR-swizzled
  int tid = threadIdx.x;
  int wid = tid >> 6, lane = tid & 63, lr = lane & 15, kg = lane >> 4;

  f32x4 acc[4] = {};
  // ap includes the per-lane kg*8 k-group offset; d-loop adds only d0+st*32.
  const unsigned short* ap = tebf + (size_t)(oq * 64 + wid * 16 + lr) * 768 + kg * 8;

  for (int d0 = 0; d0 < 768; d0 += 64) {
    #pragma unroll
    for (int p = 0; p < 4; ++p) {
      int dl = p * 16 + (tid >> 4);
      int f4 = tid & 15;
      float4 v = *reinterpret_cast<const float4*>(src + (size_t)(d0 + dl) * ld + kcol0 + f4 * 4);
      #pragma unroll
      for (int j = 0; j < 4; ++j) {
        int kk = f4 * 4 + j;
        float vj = (j == 0) ? v.x : (j == 1) ? v.y : (j == 2) ? v.z : v.w;
        s_t[kk * 64 + (dl ^ ((kk & 7) << 3))] = f2bf(vj);
      }
    }
    __syncthreads();
    #pragma unroll
    for (int st = 0; st < 2; ++st) {
      int doff = st * 32 + kg * 8;
      short8 a = *reinterpret_cast<const short8*>(ap + d0 + st * 32);
      #pragma unroll
      for (int nt = 0; nt < 4; ++nt) {
        int k16 = nt * 16 + lr;
        short8 b = *reinterpret_cast<const short8*>(s_t + k16 * 64 + (doff ^ ((k16 & 7) << 3)));
        acc[nt] = __builtin_amdgcn_mfma_f32_16x16x32_bf16(a, b, acc[nt], 0, 0, 0);
      }
    }
    __syncthreads();
  }

  #pragma unroll
  for (int nt = 0; nt < 4; ++nt) {
    #pragma unroll
    for (int r = 0; r < 4; ++r) {
      int o = oq * 64 + wid * 16 + kg * 4 + r;
      int k = kt * 64 + nt * 16 + lr;
      Wf[((size_t)e * 256 + o) * 1024 + k] = f2bf(acc[nt][r]);
    }
  }
}

// ---------------- cbias[e][o] = sum_d te[o,d]*(thb+resb)[e,d] + te_b[o] ----
__global__ __launch_bounds__(256) void cbias_kernel(const float* __restrict__ tew,
                                                    const float* __restrict__ thb,
                                                    const float* __restrict__ resb,
                                                    const float* __restrict__ teb,
                                                    float* __restrict__ cb)
{
  int e = blockIdx.x, oc = blockIdx.y;
  int tid = threadIdx.x;
  int o = oc * 16 + (tid >> 4), g = tid & 15;
  float s = 0.f;
  for (int j = 0; j < 12; ++j) {
    int d = j * 64 + g * 4;
    float4 t4 = *reinterpret_cast<const float4*>(tew + (size_t)o * 768 + d);
    float4 b1 = *reinterpret_cast<const float4*>(thb + (size_t)e * 768 + d);
    float4 b2 = *reinterpret_cast<const float4*>(resb + (size_t)e * 768 + d);
    s += t4.x * (b1.x + b2.x) + t4.y * (b1.y + b2.y) + t4.z * (b1.z + b2.z) + t4.w * (b1.w + b2.w);
  }
  #pragma unroll
  for (int m = 8; m > 0; m >>= 1) s += __shfl_xor(s, m, 64);
  if (g == 0) cb[e * 256 + o] = s + teb[o];
}

// ---------------- expert CNN tower via MFMA: 8 entries of one expert/block -
__global__ __launch_bounds__(512) void cnn_mfma(
    const unsigned short* __restrict__ flatbf, const int* __restrict__ bin,
    const int* __restrict__ cnt,
    const float* __restrict__ dw1w, const float* __restrict__ dw1b,
    const float* __restrict__ pw1w, const float* __restrict__ pw1b,
    const float* __restrict__ dw2w, const float* __restrict__ dw2b,
    const unsigned short* __restrict__ w2bf, const float* __restrict__ pw2b,
    const float* __restrict__ dw3w, const float* __restrict__ dw3b,
    const unsigned short* __restrict__ w3bf, const float* __restrict__ pw3b,
    unsigned short* __restrict__ featsbf)
{
  int e = blockIdx.x;
  int n = cnt[e];
  int chunk = blockIdx.y;
  if (chunk * 8 >= n) return;

  __shared__ __align__(16) char smem[49280];
  unsigned short* s_in = (unsigned short*)smem;            // 12288 B [en][3][16][16]
  float*          s_a  = (float*)(smem + 12288);           // 6144 B  [en][3][8][8]
  unsigned short* s_d  = (unsigned short*)smem;            // 32768 B [en][16pos][128ch swz] (over s_in+s_a)
  unsigned short* s_c  = (unsigned short*)(smem + 32768);  // 16384 B [row=en*16+pos][64ch swz]
  unsigned short* s_e3 = (unsigned short*)(smem + 32768);  // 8192 B  [row=en*4+q][128ch swz] (over s_c)
  int* s_ent = (int*)(smem + 49152);
  int* s_val = s_ent + 8;

  int tid = threadIdx.x;
  if (tid < 8) {
    int idx = chunk * 8 + tid;
    int ok = idx < n;
    s_ent[tid] = bin[e * 8192 + (ok ? idx : 0)];
    s_val[tid] = ok;
  }
  __syncthreads();

  // ---- stage 8x768 bf16 rows into LDS (12 bf16/thread) ----
  {
    int en = tid >> 6, li = tid & 63;
    int tok = s_ent[en] >> 1;
    const unsigned short* src = flatbf + (size_t)tok * 768 + li * 12;
    unsigned short* dst = s_in + en * 768 + li * 12;
    #pragma unroll
    for (int r = 0; r < 3; ++r)
      *reinterpret_cast<ushort4*>(dst + r * 4) = *reinterpret_cast<const ushort4*>(src + r * 4);
  }
  __syncthreads();

  // ---- dw1: thread=(en,c,oy) computes 8-wide output row; vector LDS reads -
  if (tid < 192) {
    int en = tid / 24, rem = tid % 24;
    int c = rem >> 3, oy = rem & 7;
    const float* w = dw1w + (e * 3 + c) * 9;
    float w0 = w[0], w1 = w[1], w2 = w[2], w3 = w[3], w4 = w[4],
          w5 = w[5], w6 = w[6], w7 = w[7], w8 = w[8];
    float bb = dw1b[e * 3 + c];
    float acc[8];
    #pragma unroll
    for (int ox = 0; ox < 8; ++ox) acc[ox] = bb;
    #pragma unroll
    for (int ky = 0; ky < 3; ++ky) {
      int iy = oy * 2 - 1 + ky;
      if ((unsigned)iy > 15u) continue;
      const unsigned short* rp = s_in + en * 768 + c * 256 + iy * 16;
      short8 lo = *reinterpret_cast<const short8*>(rp);
      short8 hi = *reinterpret_cast<const short8*>(rp + 8);
      float r[16];
      #pragma unroll
      for (int p = 0; p < 8; ++p) {
        r[p] = bf2f((unsigned short)lo[p]);
        r[8 + p] = bf2f((unsigned short)hi[p]);
      }
      float wk0 = (ky == 0) ? w0 : (ky == 1) ? w3 : w6;
      float wk1 = (ky == 0) ? w1 : (ky == 1) ? w4 : w7;
      float wk2 = (ky == 0) ? w2 : (ky == 1) ? w5 : w8;
      #pragma unroll
      for (int ox = 0; ox < 8; ++ox) {
        int ix0 = ox * 2 - 1;
        if (ix0 >= 0) acc[ox] += wk0 * r[ix0];
        acc[ox] += wk1 * r[ix0 + 1];
        acc[ox] += wk2 * r[ix0 + 2];
      }
    }
    float* sa = s_a + en * 192 + c * 64 + oy * 8;
    #pragma unroll
    for (int ox = 0; ox < 8; ++ox) sa[ox] = fmaxf(acc[ox], 0.f);
  }
  __syncthreads();

  // ---- pw1 (3->64) + dw2 (8->4) fused in registers; thread=(entry,ch) ----
  {
    int en = tid >> 6, ch = tid & 63;
    const float* w1 = pw1w + (e * 64 + ch) * 3;
    float w10 = w1[0], w11 = w1[1], w12 = w1[2];
    float b1 = pw1b[e * 64 + ch];
    float v[64];
    const float* sa = s_a + en * 192;
    #pragma unroll
    for (int p = 0; p < 64; p += 4) {
      float4 a0 = *reinterpret_cast<const float4*>(sa + p);
      float4 a1 = *reinterpret_cast<const float4*>(sa + 64 + p);
      float4 a2 = *reinterpret_cast<const float4*>(sa + 128 + p);
      v[p + 0] = fmaxf(b1 + w10 * a0.x + w11 * a1.x + w12 * a2.x, 0.f);
      v[p + 1] = fmaxf(b1 + w10 * a0.y + w11 * a1.y + w12 * a2.y, 0.f);
      v[p + 2] = fmaxf(b1 + w10 * a0.z + w11 * a1.z + w12 * a2.z, 0.f);
      v[p + 3] = fmaxf(b1 + w10 * a0.w + w11 * a1.w + w12 * a2.w, 0.f);
    }
    const float* w2d = dw2w + (e * 64 + ch) * 9;
    float b2 = dw2b[e * 64 + ch];
    #pragma unroll
    for (int oy = 0; oy < 4; ++oy) {
      #pragma unroll
      for (int ox = 0; ox < 4; ++ox) {
        float acc = b2;
        #pragma unroll
        for (int ky = 0; ky < 3; ++ky) {
          int iy = oy * 2 - 1 + ky; if ((unsigned)iy > 7u) continue;
          #pragma unroll
          for (int kx = 0; kx < 3; ++kx) {
            int ix = ox * 2 - 1 + kx; if ((unsigned)ix > 7u) continue;
            acc += w2d[ky * 3 + kx] * v[iy * 8 + ix];
          }
        }
        int row = en * 16 + oy * 4 + ox;
        int elem = ch ^ ((row & 7) << 3);
        s_c[row * 64 + elem] = f2bf(fmaxf(acc, 0.f));
      }
    }
  }
  __syncthreads();

  // ---- pw2 via MFMA: M=128(o), N=128(pos=en*16+p), K=64 ----
  {
    int wid = tid >> 6, lane = tid & 63, lr = lane & 15, kg = lane >> 4;
    f32x4 acc[8] = {};
    __builtin_amdgcn_s_setprio(1);
    #pragma unroll
    for (int ks = 0; ks < 2; ++ks) {
      int o = wid * 16 + lr;
      short8 a = *reinterpret_cast<const short8*>(w2bf + ((size_t)e * 128 + o) * 64 + ks * 32 + kg * 8);
      #pragma unroll
      for (int nt = 0; nt < 8; ++nt) {
        int row = nt * 16 + lr;
        int k0 = (ks * 32 + kg * 8) ^ ((row & 7) << 3);
        short8 b = *reinterpret_cast<const short8*>(s_c + row * 64 + k0);
        acc[nt] = __builtin_amdgcn_mfma_f32_16x16x32_bf16(a, b, acc[nt], 0, 0, 0);
      }
    }
    __builtin_amdgcn_s_setprio(0);
    int o0 = wid * 16 + kg * 4;
    float4 bb = *reinterpret_cast<const float4*>(pw2b + e * 128 + o0);
    #pragma unroll
    for (int nt = 0; nt < 8; ++nt) {
      ushort4 pk;
      pk.x = f2bf(fmaxf(acc[nt][0] + bb.x, 0.f));
      pk.y = f2bf(fmaxf(acc[nt][1] + bb.y, 0.f));
      pk.z = f2bf(fmaxf(acc[nt][2] + bb.z, 0.f));
      pk.w = f2bf(fmaxf(acc[nt][3] + bb.w, 0.f));
      *reinterpret_cast<ushort4*>(s_d + nt * 2048 + lr * 128 + (o0 ^ (lr << 3))) = pk;
    }
  }
  __syncthreads();

  // ---- dw3: thread=(en, 2-ch group); b32 vector LDS reads/stores ----
  {
    int en = tid >> 6, chg = tid & 63;
    int ch0 = chg * 2;
    float in0[16], in1[16];
    #pragma unroll
    for (int q = 0; q < 16; ++q) {
      ushort2 pr = *reinterpret_cast<const ushort2*>(s_d + en * 2048 + q * 128 + (ch0 ^ (q << 3)));
      in0[q] = bf2f(pr.x); in1[q] = bf2f(pr.y);
    }
    const float* wd = dw3w + (e * 128 + ch0) * 9;
    float b30 = dw3b[e * 128 + ch0], b31 = dw3b[e * 128 + ch0 + 1];
    #pragma unroll
    for (int oy = 0; oy < 2; ++oy) {
      #pragma unroll
      for (int ox = 0; ox < 2; ++ox) {
        float a0 = b30, a1 = b31;
        #pragma unroll
        for (int ky = 0; ky < 3; ++ky) {
          int iy = oy * 2 - 1 + ky; if ((unsigned)iy > 3u) continue;
          #pragma unroll
          for (int kx = 0; kx < 3; ++kx) {
            int ix = ox * 2 - 1 + kx; if ((unsigned)ix > 3u) continue;
            a0 += wd[ky * 3 + kx] * in0[iy * 4 + ix];
            a1 += wd[9 + ky * 3 + kx] * in1[iy * 4 + ix];
          }
        }
        int row = en * 4 + oy * 2 + ox;
        int elem = ch0 ^ ((row & 7) << 3);
        ushort2 pk;
        pk.x = f2bf(fmaxf(a0, 0.f));
        pk.y = f2bf(fmaxf(a1, 0.f));
        *reinterpret_cast<ushort2*>(s_e3 + row * 128 + elem) = pk;
      }
    }
  }
  __syncthreads();

  // ---- pw3 via MFMA: M=256(o), N=32(pos=en*4+q), K=128; relu+meanpool ----
  {
    int wid = tid >> 6, lane = tid & 63, lr = lane & 15, kg = lane >> 4;
    f32x4 acc3[2][2] = {};
    __builtin_amdgcn_s_setprio(1);
    #pragma unroll
    for (int ks = 0; ks < 4; ++ks) {
      short8 b[2];
      #pragma unroll
      for (int nb = 0; nb < 2; ++nb) {
        int row16 = nb * 16 + lr;
        int k0 = (ks * 32 + kg * 8) ^ ((row16 & 7) << 3);
        b[nb] = *reinterpret_cast<const short8*>(s_e3 + row16 * 128 + k0);
      }
      #pragma unroll
      for (int m = 0; m < 2; ++m) {
        int o = (wid * 2 + m) * 16 + lr;
        short8 a = *reinterpret_cast<const short8*>(w3bf + ((size_t)e * 256 + o) * 128 + ks * 32 + kg * 8);
        #pragma unroll
        for (int nb = 0; nb < 2; ++nb)
          acc3[m][nb] = __builtin_amdgcn_mfma_f32_16x16x32_bf16(a, b[nb], acc3[m][nb], 0, 0, 0);
      }
    }
    __builtin_amdgcn_s_setprio(0);
    #pragma unroll
    for (int nb = 0; nb < 2; ++nb) {
      int en = nb * 4 + (lr >> 2);
      int ent = s_ent[en];
      int ok = s_val[en] && ((lr & 3) == 0);
      #pragma unroll
      for (int m = 0; m < 2; ++m) {
        #pragma unroll
        for (int r = 0; r < 4; ++r) {
          int o = (wid * 2 + m) * 16 + kg * 4 + r;
          float val = fmaxf(acc3[m][nb][r] + pw3b[e * 256 + o], 0.f);
          val += __shfl_xor(val, 1, 64);
          val += __shfl_xor(val, 2, 64);
          if (ok) featsbf[(size_t)ent * 256 + o] = f2bf(val * 0.25f);
        }
      }
    }
  }
}

// ---------------- fused combine+emb GEMM via MFMA --------------------------
// 128 threads / 2 waves; 32 entries x 64 outs per block (oq picks o-quarter;
// wave picks 32-out half). Active blocks ~2048 -> 8/CU, 16 waves/CU.
// grid (32 = e*4+oq, 256 chunks).
__global__ __launch_bounds__(128) void combine5(
    const unsigned short* __restrict__ flatbf,   // [8192][768]
    const unsigned short* __restrict__ featsbf,  // [16384][256]
    const unsigned short* __restrict__ Wf,       // [8][256][1024]
    const float* __restrict__ cb,                // [8][256]
    const float* __restrict__ gval, const int* __restrict__ bin,
    const int* __restrict__ cnt, float* __restrict__ emb2)
{
  int e = blockIdx.x >> 2, oq = blockIdx.x & 3;
  int n = cnt[e];
  int chunk = blockIdx.y;
  if (chunk * 32 >= n) return;
  int tid = threadIdx.x;
  int wv = tid >> 6, lane = tid & 63;
  __shared__ int s_ent[32];
  __shared__ float s_g[32];
  __shared__ int s_ok[32];
  if (tid < 32) {
    int idx = chunk * 32 + tid;
    if (idx < n) {
      int ent = bin[e * 8192 + idx];
      s_ent[tid] = ent; s_g[tid] = gval[ent]; s_ok[tid] = 1;
    } else {
      int ent0 = bin[e * 8192];
      s_ent[tid] = ent0; s_g[tid] = 0.f; s_ok[tid] = 0;
    }
  }
  __syncthreads();

  int lr = lane & 15, kg = lane >> 4;
  int obase = oq * 64 + wv * 32;
  const unsigned short* af[2];
  #pragma unroll
  for (int i = 0; i < 2; ++i)
    af[i] = flatbf + (size_t)(s_ent[i * 16 + lr] >> 1) * 768 + kg * 8;
  const unsigned short* bp = Wf + ((size_t)e * 256 + obase + lr) * 1024 + kg * 8;

  f32x4 acc[2][2] = {};

  // K phase 1: flat path, K=768
  for (int kb = 0; kb < 768; kb += 32) {
    short8 a[2], b[2];
    #pragma unroll
    for (int i = 0; i < 2; ++i) a[i] = *reinterpret_cast<const short8*>(af[i] + kb);
    #pragma unroll
    for (int j = 0; j < 2; ++j) b[j] = *reinterpret_cast<const short8*>(bp + j * 16 * 1024 + kb);
    #pragma unroll
    for (int i = 0; i < 2; ++i)
      #pragma unroll
      for (int j = 0; j < 2; ++j)
        acc[i][j] = __builtin_amdgcn_mfma_f32_16x16x32_bf16(a[i], b[j], acc[i][j], 0, 0, 0);
  }

  // K phase 2: feats path, K=256 (Wf cols 768..1023)
  const unsigned short* at[2];
  #pragma unroll
  for (int i = 0; i < 2; ++i)
    at[i] = featsbf + (size_t)s_ent[i * 16 + lr] * 256 + kg * 8;
  for (int kb = 0; kb < 256; kb += 32) {
    short8 a[2], b[2];
    #pragma unroll
    for (int i = 0; i < 2; ++i) a[i] = *reinterpret_cast<const short8*>(at[i] + kb);
    #pragma unroll
    for (int j = 0; j < 2; ++j) b[j] = *reinterpret_cast<const short8*>(bp + j * 16 * 1024 + 768 + kb);
    #pragma unroll
    for (int i = 0; i < 2; ++i)
      #pragma unroll
      for (int j = 0; j < 2; ++j)
        acc[i][j] = __builtin_amdgcn_mfma_f32_16x16x32_bf16(a[i], b[j], acc[i][j], 0, 0, 0);
  }

  // D: col(lane&15) = o within b-tile j; row(kg*4+r) = entry within m-tile i
  #pragma unroll
  for (int j = 0; j < 2; ++j) {
    int o = obase + j * 16 + lr;
    float cbo = cb[e * 256 + o];
    #pragma unroll
    for (int i = 0; i < 2; ++i) {
      #pragma unroll
      for (int r = 0; r < 4; ++r) {
        int m = i * 16 + kg * 4 + r;
        if (s_ok[m])
          emb2[(size_t)s_ent[m] * 256 + o] = s_g[m] * (acc[i][j][r] + cbo);
      }
    }
  }
}

// ---------------- sum two entry rows per token + transposed write ----------
__global__ __launch_bounds__(256) void sum_kernel(const float* __restrict__ emb2,
                                                  float* __restrict__ out)
{
  __shared__ float s_sum[32][257];
  int tt = blockIdx.x;          // 32-token group
  int tid = threadIdx.x;
  int t0 = tt * 32;
  for (int s = 0; s < 32; ++s) {
    int t = t0 + s;
    float a = emb2[((size_t)t * 2) * 256 + tid];
    float b = emb2[((size_t)t * 2 + 1) * 256 + tid];
    s_sum[s][tid] = a + b;
  }
  __syncthreads();
  int bi = t0 >> 8, nn0 = t0 & 255;
  int s = tid & 31, oh = tid >> 5;   // 8 o-groups x 32 token-lanes
  for (int ob = 0; ob < 32; ++ob) {
    int o = ob * 8 + oh;
    out[(((size_t)bi * 256 + o) << 8) + nn0 + s] = s_sum[s][o];
  }
}

extern "C" void kernel_launch(void* const* d_in, const int* in_sizes, int n_in,
                              void* d_out, int out_size, void* d_ws, size_t ws_size,
                              hipStream_t stream)
{
  (void)in_sizes; (void)n_in; (void)out_size; (void)ws_size;
  const float* x    = (const float*)d_in[0];
  const float* gw   = (const float*)d_in[1];
  const float* gb   = (const float*)d_in[2];
  const float* dw1w = (const float*)d_in[3];
  const float* dw1b = (const float*)d_in[4];
  const float* pw1w = (const float*)d_in[5];
  const float* pw1b = (const float*)d_in[6];
  const float* dw2w = (const float*)d_in[7];
  const float* dw2b = (const float*)d_in[8];
  const float* pw2w = (const float*)d_in[9];
  const float* pw2b = (const float*)d_in[10];
  const float* dw3w = (const float*)d_in[11];
  const float* dw3b = (const float*)d_in[12];
  const float* pw3w = (const float*)d_in[13];
  const float* pw3b = (const float*)d_in[14];
  const float* thw  = (const float*)d_in[15];
  const float* thb  = (const float*)d_in[16];
  const float* resw = (const float*)d_in[17];
  const float* resb = (const float*)d_in[18];
  const float* tew  = (const float*)d_in[19];
  const float* teb  = (const float*)d_in[20];

  float* ws    = (float*)d_ws;
  float* emb2  = ws;                                           // 16384*256 f
  unsigned short* w2bf  = (unsigned short*)(ws + 6291456);     // 65536 us
  unsigned short* w3bf  = (unsigned short*)(ws + 6324224);     // 262144 us
  unsigned short* tebf  = (unsigned short*)(ws + 6455296);     // 196608 us
  unsigned short* Wf    = (unsigned short*)(ws + 6553600);     // 2097152 us (4 MB)
  float* cb    = ws + 7602176;                                 // 2048 f
  float* probs = ws + 8000000;                                 // 65536 f
  float* gval  = ws + 16777216;           // 16384 f
  int*   gidx  = (int*)(ws + 16793600);   // 16384 i
  float* aux   = ws + 16809984;           // 256 f
  int*   cnt   = (int*)(ws + 16810240);   // 8 i
  int*   bin   = (int*)(ws + 16810248);   // 65536 i
  unsigned short* flatbf  = (unsigned short*)(ws + 16875784);  // 8192*768 us
  unsigned short* featsbf = (unsigned short*)(ws + 20021512);  // 16384*256 us
  float* out   = (float*)d_out;

  hipMemsetAsync(aux, 0, 264 * sizeof(float), stream);   // aux(256) + cnt(8)

  patchgate_kernel<<<8192, 256, 0, stream>>>(x, gw, gb, flatbf, gidx, gval, probs);
  auxred_kernel<<<32, 256, 0, stream>>>(probs, gidx, aux);
  bin_kernel<<<64, 256, 0, stream>>>(gidx, cnt, bin);
  laux_kernel<<<1, 64, 0, stream>>>(aux, out);
  f2bf3_kernel<<<512, 256, 0, stream>>>(pw2w, pw3w, tew, w2bf, w3bf, tebf);

  dim3 wg(16, 4, 8);
  wfuse_kernel<<<wg, 256, 0, stream>>>(tebf, resw, thw, Wf);
  dim3 cbg(8, 16);
  cbias_kernel<<<cbg, 256, 0, stream>>>(tew, thb, resb, teb, cb);

  dim3 cnng(8, 1024);
  cnn_mfma<<<cnng, 512, 0, stream>>>(flatbf, bin, cnt, dw1w, dw1b, pw1w, pw1b,
                                     dw2w, dw2b, w2bf, pw2b, dw3w, dw3b,
                                     w3bf, pw3b, featsbf);

  dim3 cg(32, 256);
  combine5<<<cg, 128, 0, stream>>>(flatbf, featsbf, Wf, cb, gval, bin, cnt, emb2);
  sum_kernel<<<256, 256, 0, stream>>>(emb2, out);
}

// Round 17
// 263.906 us; speedup vs baseline: 1.0356x; 1.0356x over previous
//
#include <hip/hip_runtime.h>

#define NTOK 8192

typedef __attribute__((ext_vector_type(8))) short short8;
typedef __attribute__((ext_vector_type(4))) float f32x4;

__device__ __forceinline__ unsigned short f2bf(float f) {
  unsigned u = __float_as_uint(f);
  u += 0x7FFFu + ((u >> 16) & 1u);
  return (unsigned short)(u >> 16);
}
__device__ __forceinline__ float bf2f(unsigned short u) {
  return __uint_as_float(((unsigned)u) << 16);
}

// ---------------- fused patchify + gate: one block per token ---------------
__global__ __launch_bounds__(256) void patchgate_kernel(
    const float* __restrict__ x, const float* __restrict__ gw,
    const float* __restrict__ gb, unsigned short* __restrict__ flatbf,
    int* __restrict__ gidx, float* __restrict__ gval,
    float* __restrict__ probs)
{
  int t = blockIdx.x;          // 0..8191
  int tid = threadIdx.x;
  int b = t >> 8, ph = (t >> 4) & 15, pw = t & 15;
  const float* xb = x + (size_t)b * 3 * 256 * 256;
  float acc[8];
  #pragma unroll
  for (int e = 0; e < 8; ++e) acc[e] = 0.f;
  #pragma unroll
  for (int r = 0; r < 3; ++r) {
    int d = r * 256 + tid;
    int c = d >> 8, i = (d >> 4) & 15, j = d & 15;
    float v = xb[((size_t)c * 256 + ph * 16 + i) * 256 + pw * 16 + j];
    flatbf[(size_t)t * 768 + d] = f2bf(v);
    const float* g = gw + d * 8;
    #pragma unroll
    for (int e = 0; e < 8; ++e) acc[e] += v * g[e];
  }
  #pragma unroll
  for (int e = 0; e < 8; ++e) {
    #pragma unroll
    for (int off = 32; off > 0; off >>= 1)
      acc[e] += __shfl_down(acc[e], off, 64);
  }
  __shared__ float s_red[4][8];
  int wid = tid >> 6, lane = tid & 63;
  if (lane == 0) {
    #pragma unroll
    for (int e = 0; e < 8; ++e) s_red[wid][e] = acc[e];
  }
  __syncthreads();
  if (tid == 0) {
    float lg[8];
    #pragma unroll
    for (int e = 0; e < 8; ++e)
      lg[e] = s_red[0][e] + s_red[1][e] + s_red[2][e] + s_red[3][e] + gb[e];
    int i0 = 0; float v0 = lg[0];
    #pragma unroll
    for (int e = 1; e < 8; ++e) if (lg[e] > v0) { v0 = lg[e]; i0 = e; }
    int i1 = -1; float v1 = -1e30f;
    #pragma unroll
    for (int e = 0; e < 8; ++e) { if (e == i0) continue; if (lg[e] > v1) { v1 = lg[e]; i1 = e; } }
    float e1 = __expf(v1 - v0);
    float s0 = 1.f / (1.f + e1);
    float s1 = e1 * s0;
    gidx[t * 2] = i0; gidx[t * 2 + 1] = i1;
    gval[t * 2] = s0; gval[t * 2 + 1] = s1;
    float sum = 0.f, p[8];
    #pragma unroll
    for (int e = 0; e < 8; ++e) { p[e] = __expf(lg[e] - v0); sum += p[e]; }
    float inv = 1.f / sum;
    #pragma unroll
    for (int e = 0; e < 8; ++e) probs[t * 8 + e] = p[e] * inv;
  }
}

// ---------------- aux reduction: me from probs, ce from gidx ---------------
__global__ __launch_bounds__(256) void auxred_kernel(const float* __restrict__ probs,
                                                     const int* __restrict__ gidx,
                                                     float* __restrict__ aux)
{
  __shared__ float s_me[8];
  __shared__ float s_ce[8];
  int tid = threadIdx.x, lane = tid & 63;
  if (tid < 8) { s_me[tid] = 0.f; s_ce[tid] = 0.f; }
  __syncthreads();
  int t = blockIdx.x * 256 + tid;
  float p[8];
  #pragma unroll
  for (int e = 0; e < 8; ++e) p[e] = probs[t * 8 + e];
  int top1 = gidx[t * 2];
  #pragma unroll
  for (int e = 0; e < 8; ++e) {
    #pragma unroll
    for (int off = 32; off > 0; off >>= 1)
      p[e] += __shfl_down(p[e], off, 64);
  }
  if (lane == 0) {
    #pragma unroll
    for (int e = 0; e < 8; ++e) atomicAdd(&s_me[e], p[e]);
  }
  #pragma unroll
  for (int e = 0; e < 8; ++e) {
    unsigned long long m = __ballot(top1 == e);
    if (lane == 0) atomicAdd(&s_ce[e], (float)__popcll(m));
  }
  __syncthreads();
  if (tid < 8) {
    atomicAdd(&aux[tid * 16], s_ce[tid]);            // ce
    atomicAdd(&aux[128 + tid * 16], s_me[tid]);      // me
  }
}

// ---------------- bin token-slots by expert --------------------------------
__global__ __launch_bounds__(256) void bin_kernel(const int* __restrict__ gidx,
                                                  int* __restrict__ cnt,
                                                  int* __restrict__ bin)
{
  int idx = blockIdx.x * 256 + threadIdx.x;   // 0..16383 (t*2+slot)
  int e = gidx[idx];
  int pos = atomicAdd(&cnt[e], 1);
  bin[e * 8192 + pos] = idx;
}

// ---------------- l_aux finalize -------------------------------------------
__global__ void laux_kernel(const float* __restrict__ aux, float* __restrict__ out)
{
  if (threadIdx.x == 0 && blockIdx.x == 0) {
    float l = 0.f;
    for (int e = 0; e < 8; ++e)
      l += (aux[e * 16] / 8192.f) * (aux[128 + e * 16] / 8192.f);
    out[2097152] = 8.f * l;
  }
}

// ---------------- fp32 -> bf16 convert of pw2w/pw3w/tew in one launch ------
__global__ __launch_bounds__(256) void f2bf3_kernel(const float* __restrict__ a,
                                                    const float* __restrict__ b,
                                                    const float* __restrict__ c,
                                                    unsigned short* __restrict__ oa,
                                                    unsigned short* __restrict__ ob,
                                                    unsigned short* __restrict__ oc)
{
  int blk = blockIdx.x;
  const float* in; unsigned short* out; size_t base;
  if (blk < 64)       { in = a; out = oa; base = (size_t)blk * 1024; }
  else if (blk < 320) { in = b; out = ob; base = (size_t)(blk - 64) * 1024; }
  else                { in = c; out = oc; base = (size_t)(blk - 320) * 1024; }
  size_t i = base + threadIdx.x * 4;
  float4 v = *reinterpret_cast<const float4*>(in + i);
  ushort4 o;
  o.x = f2bf(v.x); o.y = f2bf(v.y); o.z = f2bf(v.z); o.w = f2bf(v.w);
  *reinterpret_cast<ushort4*>(out + i) = o;
}

// ---------------- Wfused[e][o][k] = sum_d te[o,d] * M_e[d,k] ---------------
__global__ __launch_bounds__(256) void wfuse_kernel(const unsigned short* __restrict__ tebf, // [256][768]
                                                    const float* __restrict__ resw,
                                                    const float* __restrict__ thw,
                                                    unsigned short* __restrict__ Wf)
{
  int kt = blockIdx.x, oq = blockIdx.y, e = blockIdx.z;
  const float* src; int ld, kcol0;
  if (kt < 12) { src = resw + (size_t)e * 768 * 768; ld = 768; kcol0 = kt * 64; }
  else         { src = thw + (size_t)e * 768 * 256;  ld = 256; kcol0 = (kt - 12) * 64; }

  __shared__ unsigned short s_t[64 * 64];  // [k][d] XOR-swizzled
  int tid = threadIdx.x;
  int wid = tid >> 6, lane = tid & 63, lr = lane & 15, kg = lane >> 4;

  f32x4 acc[4] = {};
  // ap includes the per-lane kg*8 k-group offset; d-loop adds only d0+st*32.
  const unsigned short* ap = tebf + (size_t)(oq * 64 + wid * 16 + lr) * 768 + kg * 8;

  for (int d0 = 0; d0 < 768; d0 += 64) {
    #pragma unroll
    for (int p = 0; p < 4; ++p) {
      int dl = p * 16 + (tid >> 4);
      int f4 = tid & 15;
      float4 v = *reinterpret_cast<const float4*>(src + (size_t)(d0 + dl) * ld + kcol0 + f4 * 4);
      #pragma unroll
      for (int j = 0; j < 4; ++j) {
        int kk = f4 * 4 + j;
        float vj = (j == 0) ? v.x : (j == 1) ? v.y : (j == 2) ? v.z : v.w;
        s_t[kk * 64 + (dl ^ ((kk & 7) << 3))] = f2bf(vj);
      }
    }
    __syncthreads();
    #pragma unroll
    for (int st = 0; st < 2; ++st) {
      int doff = st * 32 + kg * 8;
      short8 a = *reinterpret_cast<const short8*>(ap + d0 + st * 32);
      #pragma unroll
      for (int nt = 0; nt < 4; ++nt) {
        int k16 = nt * 16 + lr;
        short8 b = *reinterpret_cast<const short8*>(s_t + k16 * 64 + (doff ^ ((k16 & 7) << 3)));
        acc[nt] = __builtin_amdgcn_mfma_f32_16x16x32_bf16(a, b, acc[nt], 0, 0, 0);
      }
    }
    __syncthreads();
  }

  #pragma unroll
  for (int nt = 0; nt < 4; ++nt) {
    #pragma unroll
    for (int r = 0; r < 4; ++r) {
      int o = oq * 64 + wid * 16 + kg * 4 + r;
      int k = kt * 64 + nt * 16 + lr;
      Wf[((size_t)e * 256 + o) * 1024 + k] = f2bf(acc[nt][r]);
    }
  }
}

// ---------------- cbias[e][o] = sum_d te[o,d]*(thb+resb)[e,d] + te_b[o] ----
__global__ __launch_bounds__(256) void cbias_kernel(const float* __restrict__ tew,
                                                    const float* __restrict__ thb,
                                                    const float* __restrict__ resb,
                                                    const float* __restrict__ teb,
                                                    float* __restrict__ cb)
{
  int e = blockIdx.x, oc = blockIdx.y;
  int tid = threadIdx.x;
  int o = oc * 16 + (tid >> 4), g = tid & 15;
  float s = 0.f;
  for (int j = 0; j < 12; ++j) {
    int d = j * 64 + g * 4;
    float4 t4 = *reinterpret_cast<const float4*>(tew + (size_t)o * 768 + d);
    float4 b1 = *reinterpret_cast<const float4*>(thb + (size_t)e * 768 + d);
    float4 b2 = *reinterpret_cast<const float4*>(resb + (size_t)e * 768 + d);
    s += t4.x * (b1.x + b2.x) + t4.y * (b1.y + b2.y) + t4.z * (b1.z + b2.z) + t4.w * (b1.w + b2.w);
  }
  #pragma unroll
  for (int m = 8; m > 0; m >>= 1) s += __shfl_xor(s, m, 64);
  if (g == 0) cb[e * 256 + o] = s + teb[o];
}

// ---------------- expert CNN tower via MFMA: 8 entries of one expert/block -
__global__ __launch_bounds__(512) void cnn_mfma(
    const unsigned short* __restrict__ flatbf, const int* __restrict__ bin,
    const int* __restrict__ cnt,
    const float* __restrict__ dw1w, const float* __restrict__ dw1b,
    const float* __restrict__ pw1w, const float* __restrict__ pw1b,
    const float* __restrict__ dw2w, const float* __restrict__ dw2b,
    const unsigned short* __restrict__ w2bf, const float* __restrict__ pw2b,
    const float* __restrict__ dw3w, const float* __restrict__ dw3b,
    const unsigned short* __restrict__ w3bf, const float* __restrict__ pw3b,
    unsigned short* __restrict__ featsbf)
{
  int e = blockIdx.x;
  int n = cnt[e];
  int chunk = blockIdx.y;
  if (chunk * 8 >= n) return;

  __shared__ __align__(16) char smem[49280];
  unsigned short* s_in = (unsigned short*)smem;            // 12288 B [en][3][16][16]
  float*          s_a  = (float*)(smem + 12288);           // 6144 B  [en][3][8][8]
  unsigned short* s_d  = (unsigned short*)smem;            // 32768 B [en][16pos][128ch swz] (over s_in+s_a)
  unsigned short* s_c  = (unsigned short*)(smem + 32768);  // 16384 B [row=en*16+pos][64ch swz]
  unsigned short* s_e3 = (unsigned short*)(smem + 32768);  // 8192 B  [row=en*4+q][128ch swz] (over s_c)
  int* s_ent = (int*)(smem + 49152);
  int* s_val = s_ent + 8;

  int tid = threadIdx.x;
  if (tid < 8) {
    int idx = chunk * 8 + tid;
    int ok = idx < n;
    s_ent[tid] = bin[e * 8192 + (ok ? idx : 0)];
    s_val[tid] = ok;
  }
  __syncthreads();

  // ---- stage 8x768 bf16 rows into LDS (12 bf16/thread) ----
  {
    int en = tid >> 6, li = tid & 63;
    int tok = s_ent[en] >> 1;
    const unsigned short* src = flatbf + (size_t)tok * 768 + li * 12;
    unsigned short* dst = s_in + en * 768 + li * 12;
    #pragma unroll
    for (int r = 0; r < 3; ++r)
      *reinterpret_cast<ushort4*>(dst + r * 4) = *reinterpret_cast<const ushort4*>(src + r * 4);
  }
  __syncthreads();

  // ---- dw1: thread=(en,c,oy) computes 8-wide output row; vector LDS reads -
  if (tid < 192) {
    int en = tid / 24, rem = tid % 24;
    int c = rem >> 3, oy = rem & 7;
    const float* w = dw1w + (e * 3 + c) * 9;
    float w0 = w[0], w1 = w[1], w2 = w[2], w3 = w[3], w4 = w[4],
          w5 = w[5], w6 = w[6], w7 = w[7], w8 = w[8];
    float bb = dw1b[e * 3 + c];
    float acc[8];
    #pragma unroll
    for (int ox = 0; ox < 8; ++ox) acc[ox] = bb;
    #pragma unroll
    for (int ky = 0; ky < 3; ++ky) {
      int iy = oy * 2 - 1 + ky;
      if ((unsigned)iy > 15u) continue;
      const unsigned short* rp = s_in + en * 768 + c * 256 + iy * 16;
      short8 lo = *reinterpret_cast<const short8*>(rp);
      short8 hi = *reinterpret_cast<const short8*>(rp + 8);
      float r[16];
      #pragma unroll
      for (int p = 0; p < 8; ++p) {
        r[p] = bf2f((unsigned short)lo[p]);
        r[8 + p] = bf2f((unsigned short)hi[p]);
      }
      float wk0 = (ky == 0) ? w0 : (ky == 1) ? w3 : w6;
      float wk1 = (ky == 0) ? w1 : (ky == 1) ? w4 : w7;
      float wk2 = (ky == 0) ? w2 : (ky == 1) ? w5 : w8;
      #pragma unroll
      for (int ox = 0; ox < 8; ++ox) {
        int ix0 = ox * 2 - 1;
        if (ix0 >= 0) acc[ox] += wk0 * r[ix0];
        acc[ox] += wk1 * r[ix0 + 1];
        acc[ox] += wk2 * r[ix0 + 2];
      }
    }
    float* sa = s_a + en * 192 + c * 64 + oy * 8;
    #pragma unroll
    for (int ox = 0; ox < 8; ++ox) sa[ox] = fmaxf(acc[ox], 0.f);
  }
  __syncthreads();

  // ---- pw1 (3->64) + dw2 (8->4) fused in registers; thread=(entry,ch) ----
  {
    int en = tid >> 6, ch = tid & 63;
    const float* w1 = pw1w + (e * 64 + ch) * 3;
    float w10 = w1[0], w11 = w1[1], w12 = w1[2];
    float b1 = pw1b[e * 64 + ch];
    float v[64];
    const float* sa = s_a + en * 192;
    #pragma unroll
    for (int p = 0; p < 64; p += 4) {
      float4 a0 = *reinterpret_cast<const float4*>(sa + p);
      float4 a1 = *reinterpret_cast<const float4*>(sa + 64 + p);
      float4 a2 = *reinterpret_cast<const float4*>(sa + 128 + p);
      v[p + 0] = fmaxf(b1 + w10 * a0.x + w11 * a1.x + w12 * a2.x, 0.f);
      v[p + 1] = fmaxf(b1 + w10 * a0.y + w11 * a1.y + w12 * a2.y, 0.f);
      v[p + 2] = fmaxf(b1 + w10 * a0.z + w11 * a1.z + w12 * a2.z, 0.f);
      v[p + 3] = fmaxf(b1 + w10 * a0.w + w11 * a1.w + w12 * a2.w, 0.f);
    }
    const float* w2d = dw2w + (e * 64 + ch) * 9;
    float b2 = dw2b[e * 64 + ch];
    #pragma unroll
    for (int oy = 0; oy < 4; ++oy) {
      #pragma unroll
      for (int ox = 0; ox < 4; ++ox) {
        float acc = b2;
        #pragma unroll
        for (int ky = 0; ky < 3; ++ky) {
          int iy = oy * 2 - 1 + ky; if ((unsigned)iy > 7u) continue;
          #pragma unroll
          for (int kx = 0; kx < 3; ++kx) {
            int ix = ox * 2 - 1 + kx; if ((unsigned)ix > 7u) continue;
            acc += w2d[ky * 3 + kx] * v[iy * 8 + ix];
          }
        }
        int row = en * 16 + oy * 4 + ox;
        int elem = ch ^ ((row & 7) << 3);
        s_c[row * 64 + elem] = f2bf(fmaxf(acc, 0.f));
      }
    }
  }
  __syncthreads();

  // ---- pw2 via MFMA: M=128(o), N=128(pos=en*16+p), K=64 ----
  {
    int wid = tid >> 6, lane = tid & 63, lr = lane & 15, kg = lane >> 4;
    f32x4 acc[8] = {};
    #pragma unroll
    for (int ks = 0; ks < 2; ++ks) {
      int o = wid * 16 + lr;
      short8 a = *reinterpret_cast<const short8*>(w2bf + ((size_t)e * 128 + o) * 64 + ks * 32 + kg * 8);
      #pragma unroll
      for (int nt = 0; nt < 8; ++nt) {
        int row = nt * 16 + lr;
        int k0 = (ks * 32 + kg * 8) ^ ((row & 7) << 3);
        short8 b = *reinterpret_cast<const short8*>(s_c + row * 64 + k0);
        acc[nt] = __builtin_amdgcn_mfma_f32_16x16x32_bf16(a, b, acc[nt], 0, 0, 0);
      }
    }
    int o0 = wid * 16 + kg * 4;
    float4 bb = *reinterpret_cast<const float4*>(pw2b + e * 128 + o0);
    #pragma unroll
    for (int nt = 0; nt < 8; ++nt) {
      ushort4 pk;
      pk.x = f2bf(fmaxf(acc[nt][0] + bb.x, 0.f));
      pk.y = f2bf(fmaxf(acc[nt][1] + bb.y, 0.f));
      pk.z = f2bf(fmaxf(acc[nt][2] + bb.z, 0.f));
      pk.w = f2bf(fmaxf(acc[nt][3] + bb.w, 0.f));
      *reinterpret_cast<ushort4*>(s_d + nt * 2048 + lr * 128 + (o0 ^ (lr << 3))) = pk;
    }
  }
  __syncthreads();

  // ---- dw3: thread=(en, 2-ch group); b32 vector LDS reads/stores ----
  {
    int en = tid >> 6, chg = tid & 63;
    int ch0 = chg * 2;
    float in0[16], in1[16];
    #pragma unroll
    for (int q = 0; q < 16; ++q) {
      ushort2 pr = *reinterpret_cast<const ushort2*>(s_d + en * 2048 + q * 128 + (ch0 ^ (q << 3)));
      in0[q] = bf2f(pr.x); in1[q] = bf2f(pr.y);
    }
    const float* wd = dw3w + (e * 128 + ch0) * 9;
    float b30 = dw3b[e * 128 + ch0], b31 = dw3b[e * 128 + ch0 + 1];
    #pragma unroll
    for (int oy = 0; oy < 2; ++oy) {
      #pragma unroll
      for (int ox = 0; ox < 2; ++ox) {
        float a0 = b30, a1 = b31;
        #pragma unroll
        for (int ky = 0; ky < 3; ++ky) {
          int iy = oy * 2 - 1 + ky; if ((unsigned)iy > 3u) continue;
          #pragma unroll
          for (int kx = 0; kx < 3; ++kx) {
            int ix = ox * 2 - 1 + kx; if ((unsigned)ix > 3u) continue;
            a0 += wd[ky * 3 + kx] * in0[iy * 4 + ix];
            a1 += wd[9 + ky * 3 + kx] * in1[iy * 4 + ix];
          }
        }
        int row = en * 4 + oy * 2 + ox;
        int elem = ch0 ^ ((row & 7) << 3);
        ushort2 pk;
        pk.x = f2bf(fmaxf(a0, 0.f));
        pk.y = f2bf(fmaxf(a1, 0.f));
        *reinterpret_cast<ushort2*>(s_e3 + row * 128 + elem) = pk;
      }
    }
  }
  __syncthreads();

  // ---- pw3 via MFMA: M=256(o), N=32(pos=en*4+q), K=128; relu+meanpool ----
  {
    int wid = tid >> 6, lane = tid & 63, lr = lane & 15, kg = lane >> 4;
    f32x4 acc3[2][2] = {};
    #pragma unroll
    for (int ks = 0; ks < 4; ++ks) {
      short8 b[2];
      #pragma unroll
      for (int nb = 0; nb < 2; ++nb) {
        int row16 = nb * 16 + lr;
        int k0 = (ks * 32 + kg * 8) ^ ((row16 & 7) << 3);
        b[nb] = *reinterpret_cast<const short8*>(s_e3 + row16 * 128 + k0);
      }
      #pragma unroll
      for (int m = 0; m < 2; ++m) {
        int o = (wid * 2 + m) * 16 + lr;
        short8 a = *reinterpret_cast<const short8*>(w3bf + ((size_t)e * 256 + o) * 128 + ks * 32 + kg * 8);
        #pragma unroll
        for (int nb = 0; nb < 2; ++nb)
          acc3[m][nb] = __builtin_amdgcn_mfma_f32_16x16x32_bf16(a, b[nb], acc3[m][nb], 0, 0, 0);
      }
    }
    #pragma unroll
    for (int nb = 0; nb < 2; ++nb) {
      int en = nb * 4 + (lr >> 2);
      int ent = s_ent[en];
      int ok = s_val[en] && ((lr & 3) == 0);
      #pragma unroll
      for (int m = 0; m < 2; ++m) {
        #pragma unroll
        for (int r = 0; r < 4; ++r) {
          int o = (wid * 2 + m) * 16 + kg * 4 + r;
          float val = fmaxf(acc3[m][nb][r] + pw3b[e * 256 + o], 0.f);
          val += __shfl_xor(val, 1, 64);
          val += __shfl_xor(val, 2, 64);
          if (ok) featsbf[(size_t)ent * 256 + o] = f2bf(val * 0.25f);
        }
      }
    }
  }
}

// ---------------- fused combine+emb GEMM via MFMA --------------------------
// 128 threads / 2 waves; 32 entries x 128 outs per block (oh picks o-half).
__global__ __launch_bounds__(128) void combine4(
    const unsigned short* __restrict__ flatbf,   // [8192][768]
    const unsigned short* __restrict__ featsbf,  // [16384][256]
    const unsigned short* __restrict__ Wf,       // [8][256][1024]
    const float* __restrict__ cb,                // [8][256]
    const float* __restrict__ gval, const int* __restrict__ bin,
    const int* __restrict__ cnt, float* __restrict__ emb2)
{
  int e = blockIdx.x >> 1, oh = blockIdx.x & 1;
  int n = cnt[e];
  int chunk = blockIdx.y;
  if (chunk * 32 >= n) return;
  int tid = threadIdx.x;
  int wv = tid >> 6, lane = tid & 63;
  __shared__ int s_ent[32];
  __shared__ float s_g[32];
  __shared__ int s_ok[32];
  if (tid < 32) {
    int idx = chunk * 32 + tid;
    if (idx < n) {
      int ent = bin[e * 8192 + idx];
      s_ent[tid] = ent; s_g[tid] = gval[ent]; s_ok[tid] = 1;
    } else {
      int ent0 = bin[e * 8192];
      s_ent[tid] = ent0; s_g[tid] = 0.f; s_ok[tid] = 0;
    }
  }
  __syncthreads();

  int lr = lane & 15, kg = lane >> 4;
  int obase = oh * 128 + wv * 64;
  const unsigned short* af[2];
  #pragma unroll
  for (int i = 0; i < 2; ++i)
    af[i] = flatbf + (size_t)(s_ent[i * 16 + lr] >> 1) * 768 + kg * 8;
  const unsigned short* bp = Wf + ((size_t)e * 256 + obase + lr) * 1024 + kg * 8;

  f32x4 acc[2][4] = {};

  // K phase 1: flat path, K=768
  for (int kb = 0; kb < 768; kb += 32) {
    short8 a[2], b[4];
    #pragma unroll
    for (int i = 0; i < 2; ++i) a[i] = *reinterpret_cast<const short8*>(af[i] + kb);
    #pragma unroll
    for (int j = 0; j < 4; ++j) b[j] = *reinterpret_cast<const short8*>(bp + j * 16 * 1024 + kb);
    #pragma unroll
    for (int i = 0; i < 2; ++i)
      #pragma unroll
      for (int j = 0; j < 4; ++j)
        acc[i][j] = __builtin_amdgcn_mfma_f32_16x16x32_bf16(a[i], b[j], acc[i][j], 0, 0, 0);
  }

  // K phase 2: feats path, K=256 (Wf cols 768..1023)
  const unsigned short* at[2];
  #pragma unroll
  for (int i = 0; i < 2; ++i)
    at[i] = featsbf + (size_t)s_ent[i * 16 + lr] * 256 + kg * 8;
  for (int kb = 0; kb < 256; kb += 32) {
    short8 a[2], b[4];
    #pragma unroll
    for (int i = 0; i < 2; ++i) a[i] = *reinterpret_cast<const short8*>(at[i] + kb);
    #pragma unroll
    for (int j = 0; j < 4; ++j) b[j] = *reinterpret_cast<const short8*>(bp + j * 16 * 1024 + 768 + kb);
    #pragma unroll
    for (int i = 0; i < 2; ++i)
      #pragma unroll
      for (int j = 0; j < 4; ++j)
        acc[i][j] = __builtin_amdgcn_mfma_f32_16x16x32_bf16(a[i], b[j], acc[i][j], 0, 0, 0);
  }

  // D: col(lane&15) = o within b-tile j; row(kg*4+r) = entry within m-tile i
  #pragma unroll
  for (int j = 0; j < 4; ++j) {
    int o = obase + j * 16 + lr;
    float cbo = cb[e * 256 + o];
    #pragma unroll
    for (int i = 0; i < 2; ++i) {
      #pragma unroll
      for (int r = 0; r < 4; ++r) {
        int m = i * 16 + kg * 4 + r;
        if (s_ok[m])
          emb2[(size_t)s_ent[m] * 256 + o] = s_g[m] * (acc[i][j][r] + cbo);
      }
    }
  }
}

// ---------------- sum two entry rows per token + transposed write ----------
__global__ __launch_bounds__(256) void sum_kernel(const float* __restrict__ emb2,
                                                  float* __restrict__ out)
{
  __shared__ float s_sum[32][257];
  int tt = blockIdx.x;          // 32-token group
  int tid = threadIdx.x;
  int t0 = tt * 32;
  for (int s = 0; s < 32; ++s) {
    int t = t0 + s;
    float a = emb2[((size_t)t * 2) * 256 + tid];
    float b = emb2[((size_t)t * 2 + 1) * 256 + tid];
    s_sum[s][tid] = a + b;
  }
  __syncthreads();
  int bi = t0 >> 8, nn0 = t0 & 255;
  int s = tid & 31, oh = tid >> 5;   // 8 o-groups x 32 token-lanes
  for (int ob = 0; ob < 32; ++ob) {
    int o = ob * 8 + oh;
    out[(((size_t)bi * 256 + o) << 8) + nn0 + s] = s_sum[s][o];
  }
}

extern "C" void kernel_launch(void* const* d_in, const int* in_sizes, int n_in,
                              void* d_out, int out_size, void* d_ws, size_t ws_size,
                              hipStream_t stream)
{
  (void)in_sizes; (void)n_in; (void)out_size; (void)ws_size;
  const float* x    = (const float*)d_in[0];
  const float* gw   = (const float*)d_in[1];
  const float* gb   = (const float*)d_in[2];
  const float* dw1w = (const float*)d_in[3];
  const float* dw1b = (const float*)d_in[4];
  const float* pw1w = (const float*)d_in[5];
  const float* pw1b = (const float*)d_in[6];
  const float* dw2w = (const float*)d_in[7];
  const float* dw2b = (const float*)d_in[8];
  const float* pw2w = (const float*)d_in[9];
  const float* pw2b = (const float*)d_in[10];
  const float* dw3w = (const float*)d_in[11];
  const float* dw3b = (const float*)d_in[12];
  const float* pw3w = (const float*)d_in[13];
  const float* pw3b = (const float*)d_in[14];
  const float* thw  = (const float*)d_in[15];
  const float* thb  = (const float*)d_in[16];
  const float* resw = (const float*)d_in[17];
  const float* resb = (const float*)d_in[18];
  const float* tew  = (const float*)d_in[19];
  const float* teb  = (const float*)d_in[20];

  float* ws    = (float*)d_ws;
  float* emb2  = ws;                                           // 16384*256 f
  unsigned short* w2bf  = (unsigned short*)(ws + 6291456);     // 65536 us
  unsigned short* w3bf  = (unsigned short*)(ws + 6324224);     // 262144 us
  unsigned short* tebf  = (unsigned short*)(ws + 6455296);     // 196608 us
  unsigned short* Wf    = (unsigned short*)(ws + 6553600);     // 2097152 us (4 MB)
  float* cb    = ws + 7602176;                                 // 2048 f
  float* probs = ws + 8000000;                                 // 65536 f
  float* gval  = ws + 16777216;           // 16384 f
  int*   gidx  = (int*)(ws + 16793600);   // 16384 i
  float* aux   = ws + 16809984;           // 256 f
  int*   cnt   = (int*)(ws + 16810240);   // 8 i
  int*   bin   = (int*)(ws + 16810248);   // 65536 i
  unsigned short* flatbf  = (unsigned short*)(ws + 16875784);  // 8192*768 us
  unsigned short* featsbf = (unsigned short*)(ws + 20021512);  // 16384*256 us
  float* out   = (float*)d_out;

  hipMemsetAsync(aux, 0, 264 * sizeof(float), stream);   // aux(256) + cnt(8)

  patchgate_kernel<<<8192, 256, 0, stream>>>(x, gw, gb, flatbf, gidx, gval, probs);
  auxred_kernel<<<32, 256, 0, stream>>>(probs, gidx, aux);
  bin_kernel<<<64, 256, 0, stream>>>(gidx, cnt, bin);
  laux_kernel<<<1, 64, 0, stream>>>(aux, out);
  f2bf3_kernel<<<512, 256, 0, stream>>>(pw2w, pw3w, tew, w2bf, w3bf, tebf);

  dim3 wg(16, 4, 8);
  wfuse_kernel<<<wg, 256, 0, stream>>>(tebf, resw, thw, Wf);
  dim3 cbg(8, 16);
  cbias_kernel<<<cbg, 256, 0, stream>>>(tew, thb, resb, teb, cb);

  dim3 cnng(8, 1024);
  cnn_mfma<<<cnng, 512, 0, stream>>>(flatbf, bin, cnt, dw1w, dw1b, pw1w, pw1b,
                                     dw2w, dw2b, w2bf, pw2b, dw3w, dw3b,
                                     w3bf, pw3b, featsbf);

  dim3 cg(16, 256);
  combine4<<<cg, 128, 0, stream>>>(flatbf, featsbf, Wf, cb, gval, bin, cnt, emb2);
  sum_kernel<<<256, 256, 0, stream>>>(emb2, out);
}

// Round 18
// 261.255 us; speedup vs baseline: 1.0461x; 1.0101x over previous
//
#include <hip/hip_runtime.h>

#define NTOK 8192

typedef __attribute__((ext_vector_type(8))) short short8;
typedef __attribute__((ext_vector_type(4))) float f32x4;

__device__ __forceinline__ unsigned short f2bf(float f) {
  unsigned u = __float_as_uint(f);
  u += 0x7FFFu + ((u >> 16) & 1u);
  return (unsigned short)(u >> 16);
}
__device__ __forceinline__ float bf2f(unsigned short u) {
  return __uint_as_float(((unsigned)u) << 16);
}

// ---------------- fused patchify + gate: one block per token ---------------
__global__ __launch_bounds__(256) void patchgate_kernel(
    const float* __restrict__ x, const float* __restrict__ gw,
    const float* __restrict__ gb, unsigned short* __restrict__ flatbf,
    int* __restrict__ gidx, float* __restrict__ gval,
    float* __restrict__ probs)
{
  int t = blockIdx.x;          // 0..8191
  int tid = threadIdx.x;
  int b = t >> 8, ph = (t >> 4) & 15, pw = t & 15;
  const float* xb = x + (size_t)b * 3 * 256 * 256;
  float acc[8];
  #pragma unroll
  for (int e = 0; e < 8; ++e) acc[e] = 0.f;
  #pragma unroll
  for (int r = 0; r < 3; ++r) {
    int d = r * 256 + tid;
    int c = d >> 8, i = (d >> 4) & 15, j = d & 15;
    float v = xb[((size_t)c * 256 + ph * 16 + i) * 256 + pw * 16 + j];
    flatbf[(size_t)t * 768 + d] = f2bf(v);
    const float* g = gw + d * 8;
    #pragma unroll
    for (int e = 0; e < 8; ++e) acc[e] += v * g[e];
  }
  #pragma unroll
  for (int e = 0; e < 8; ++e) {
    #pragma unroll
    for (int off = 32; off > 0; off >>= 1)
      acc[e] += __shfl_down(acc[e], off, 64);
  }
  __shared__ float s_red[4][8];
  int wid = tid >> 6, lane = tid & 63;
  if (lane == 0) {
    #pragma unroll
    for (int e = 0; e < 8; ++e) s_red[wid][e] = acc[e];
  }
  __syncthreads();
  if (tid == 0) {
    float lg[8];
    #pragma unroll
    for (int e = 0; e < 8; ++e)
      lg[e] = s_red[0][e] + s_red[1][e] + s_red[2][e] + s_red[3][e] + gb[e];
    int i0 = 0; float v0 = lg[0];
    #pragma unroll
    for (int e = 1; e < 8; ++e) if (lg[e] > v0) { v0 = lg[e]; i0 = e; }
    int i1 = -1; float v1 = -1e30f;
    #pragma unroll
    for (int e = 0; e < 8; ++e) { if (e == i0) continue; if (lg[e] > v1) { v1 = lg[e]; i1 = e; } }
    float e1 = __expf(v1 - v0);
    float s0 = 1.f / (1.f + e1);
    float s1 = e1 * s0;
    gidx[t * 2] = i0; gidx[t * 2 + 1] = i1;
    gval[t * 2] = s0; gval[t * 2 + 1] = s1;
    float sum = 0.f, p[8];
    #pragma unroll
    for (int e = 0; e < 8; ++e) { p[e] = __expf(lg[e] - v0); sum += p[e]; }
    float inv = 1.f / sum;
    #pragma unroll
    for (int e = 0; e < 8; ++e) probs[t * 8 + e] = p[e] * inv;
  }
}

// ---------------- aux reduction: me from probs, ce from gidx ---------------
__global__ __launch_bounds__(256) void auxred_kernel(const float* __restrict__ probs,
                                                     const int* __restrict__ gidx,
                                                     float* __restrict__ aux)
{
  __shared__ float s_me[8];
  __shared__ float s_ce[8];
  int tid = threadIdx.x, lane = tid & 63;
  if (tid < 8) { s_me[tid] = 0.f; s_ce[tid] = 0.f; }
  __syncthreads();
  int t = blockIdx.x * 256 + tid;
  float p[8];
  #pragma unroll
  for (int e = 0; e < 8; ++e) p[e] = probs[t * 8 + e];
  int top1 = gidx[t * 2];
  #pragma unroll
  for (int e = 0; e < 8; ++e) {
    #pragma unroll
    for (int off = 32; off > 0; off >>= 1)
      p[e] += __shfl_down(p[e], off, 64);
  }
  if (lane == 0) {
    #pragma unroll
    for (int e = 0; e < 8; ++e) atomicAdd(&s_me[e], p[e]);
  }
  #pragma unroll
  for (int e = 0; e < 8; ++e) {
    unsigned long long m = __ballot(top1 == e);
    if (lane == 0) atomicAdd(&s_ce[e], (float)__popcll(m));
  }
  __syncthreads();
  if (tid < 8) {
    atomicAdd(&aux[tid * 16], s_ce[tid]);            // ce
    atomicAdd(&aux[128 + tid * 16], s_me[tid]);      // me
  }
}

// ---------------- bin token-slots by expert --------------------------------
__global__ __launch_bounds__(256) void bin_kernel(const int* __restrict__ gidx,
                                                  int* __restrict__ cnt,
                                                  int* __restrict__ bin)
{
  int idx = blockIdx.x * 256 + threadIdx.x;   // 0..16383 (t*2+slot)
  int e = gidx[idx];
  int pos = atomicAdd(&cnt[e], 1);
  bin[e * 8192 + pos] = idx;
}

// ---------------- l_aux finalize -------------------------------------------
__global__ void laux_kernel(const float* __restrict__ aux, float* __restrict__ out)
{
  if (threadIdx.x == 0 && blockIdx.x == 0) {
    float l = 0.f;
    for (int e = 0; e < 8; ++e)
      l += (aux[e * 16] / 8192.f) * (aux[128 + e * 16] / 8192.f);
    out[2097152] = 8.f * l;
  }
}

// ---------------- fp32 -> bf16 convert of pw2w/pw3w/tew in one launch ------
__global__ __launch_bounds__(256) void f2bf3_kernel(const float* __restrict__ a,
                                                    const float* __restrict__ b,
                                                    const float* __restrict__ c,
                                                    unsigned short* __restrict__ oa,
                                                    unsigned short* __restrict__ ob,
                                                    unsigned short* __restrict__ oc)
{
  int blk = blockIdx.x;
  const float* in; unsigned short* out; size_t base;
  if (blk < 64)       { in = a; out = oa; base = (size_t)blk * 1024; }
  else if (blk < 320) { in = b; out = ob; base = (size_t)(blk - 64) * 1024; }
  else                { in = c; out = oc; base = (size_t)(blk - 320) * 1024; }
  size_t i = base + threadIdx.x * 4;
  float4 v = *reinterpret_cast<const float4*>(in + i);
  ushort4 o;
  o.x = f2bf(v.x); o.y = f2bf(v.y); o.z = f2bf(v.z); o.w = f2bf(v.w);
  *reinterpret_cast<ushort4*>(out + i) = o;
}

// ---------------- Wfused[e][o][k] = sum_d te[o,d] * M_e[d,k] ---------------
__global__ __launch_bounds__(256) void wfuse_kernel(const unsigned short* __restrict__ tebf, // [256][768]
                                                    const float* __restrict__ resw,
                                                    const float* __restrict__ thw,
                                                    unsigned short* __restrict__ Wf)
{
  int kt = blockIdx.x, oq = blockIdx.y, e = blockIdx.z;
  const float* src; int ld, kcol0;
  if (kt < 12) { src = resw + (size_t)e * 768 * 768; ld = 768; kcol0 = kt * 64; }
  else         { src = thw + (size_t)e * 768 * 256;  ld = 256; kcol0 = (kt - 12) * 64; }

  __shared__ unsigned short s_t[64 * 64];  // [k][d] XOR-swizzled
  int tid = threadIdx.x;
  int wid = tid >> 6, lane = tid & 63, lr = lane & 15, kg = lane >> 4;

  f32x4 acc[4] = {};
  // ap includes the per-lane kg*8 k-group offset; d-loop adds only d0+st*32.
  const unsigned short* ap = tebf + (size_t)(oq * 64 + wid * 16 + lr) * 768 + kg * 8;

  for (int d0 = 0; d0 < 768; d0 += 64) {
    #pragma unroll
    for (int p = 0; p < 4; ++p) {
      int dl = p * 16 + (tid >> 4);
      int f4 = tid & 15;
      float4 v = *reinterpret_cast<const float4*>(src + (size_t)(d0 + dl) * ld + kcol0 + f4 * 4);
      #pragma unroll
      for (int j = 0; j < 4; ++j) {
        int kk = f4 * 4 + j;
        float vj = (j == 0) ? v.x : (j == 1) ? v.y : (j == 2) ? v.z : v.w;
        s_t[kk * 64 + (dl ^ ((kk & 7) << 3))] = f2bf(vj);
      }
    }
    __syncthreads();
    #pragma unroll
    for (int st = 0; st < 2; ++st) {
      int doff = st * 32 + kg * 8;
      short8 a = *reinterpret_cast<const short8*>(ap + d0 + st * 32);
      #pragma unroll
      for (int nt = 0; nt < 4; ++nt) {
        int k16 = nt * 16 + lr;
        short8 b = *reinterpret_cast<const short8*>(s_t + k16 * 64 + (doff ^ ((k16 & 7) << 3)));
        acc[nt] = __builtin_amdgcn_mfma_f32_16x16x32_bf16(a, b, acc[nt], 0, 0, 0);
      }
    }
    __syncthreads();
  }

  #pragma unroll
  for (int nt = 0; nt < 4; ++nt) {
    #pragma unroll
    for (int r = 0; r < 4; ++r) {
      int o = oq * 64 + wid * 16 + kg * 4 + r;
      int k = kt * 64 + nt * 16 + lr;
      Wf[((size_t)e * 256 + o) * 1024 + k] = f2bf(acc[nt][r]);
    }
  }
}

// ---------------- cbias[e][o] = sum_d te[o,d]*(thb+resb)[e,d] + te_b[o] ----
__global__ __launch_bounds__(256) void cbias_kernel(const float* __restrict__ tew,
                                                    const float* __restrict__ thb,
                                                    const float* __restrict__ resb,
                                                    const float* __restrict__ teb,
                                                    float* __restrict__ cb)
{
  int e = blockIdx.x, oc = blockIdx.y;
  int tid = threadIdx.x;
  int o = oc * 16 + (tid >> 4), g = tid & 15;
  float s = 0.f;
  for (int j = 0; j < 12; ++j) {
    int d = j * 64 + g * 4;
    float4 t4 = *reinterpret_cast<const float4*>(tew + (size_t)o * 768 + d);
    float4 b1 = *reinterpret_cast<const float4*>(thb + (size_t)e * 768 + d);
    float4 b2 = *reinterpret_cast<const float4*>(resb + (size_t)e * 768 + d);
    s += t4.x * (b1.x + b2.x) + t4.y * (b1.y + b2.y) + t4.z * (b1.z + b2.z) + t4.w * (b1.w + b2.w);
  }
  #pragma unroll
  for (int m = 8; m > 0; m >>= 1) s += __shfl_xor(s, m, 64);
  if (g == 0) cb[e * 256 + o] = s + teb[o];
}

// ---------------- expert CNN tower via MFMA: 8 entries of one expert/block -
// dw1 reads flatbf directly from global (s_in staging removed; rows L2-hot).
__global__ __launch_bounds__(512) void cnn_mfma(
    const unsigned short* __restrict__ flatbf, const int* __restrict__ bin,
    const int* __restrict__ cnt,
    const float* __restrict__ dw1w, const float* __restrict__ dw1b,
    const float* __restrict__ pw1w, const float* __restrict__ pw1b,
    const float* __restrict__ dw2w, const float* __restrict__ dw2b,
    const unsigned short* __restrict__ w2bf, const float* __restrict__ pw2b,
    const float* __restrict__ dw3w, const float* __restrict__ dw3b,
    const unsigned short* __restrict__ w3bf, const float* __restrict__ pw3b,
    unsigned short* __restrict__ featsbf)
{
  int e = blockIdx.x;
  int n = cnt[e];
  int chunk = blockIdx.y;
  if (chunk * 8 >= n) return;

  __shared__ __align__(16) char smem[49280];
  float*          s_a  = (float*)smem;                     // 6144 B  [en][3][8][8]
  unsigned short* s_d  = (unsigned short*)smem;            // 32768 B [en][16pos][128ch swz] (over s_a)
  unsigned short* s_c  = (unsigned short*)(smem + 32768);  // 16384 B [row=en*16+pos][64ch swz]
  unsigned short* s_e3 = (unsigned short*)(smem + 32768);  // 8192 B  [row=en*4+q][128ch swz] (over s_c)
  int* s_ent = (int*)(smem + 49152);
  int* s_val = s_ent + 8;

  int tid = threadIdx.x;
  if (tid < 8) {
    int idx = chunk * 8 + tid;
    int ok = idx < n;
    s_ent[tid] = bin[e * 8192 + (ok ? idx : 0)];
    s_val[tid] = ok;
  }
  __syncthreads();

  // ---- dw1: thread=(en,c,oy) computes 8-wide output row; global vec reads -
  if (tid < 192) {
    int en = tid / 24, rem = tid % 24;
    int c = rem >> 3, oy = rem & 7;
    int tok = s_ent[en] >> 1;
    const unsigned short* base = flatbf + (size_t)tok * 768 + c * 256;
    const float* w = dw1w + (e * 3 + c) * 9;
    float w0 = w[0], w1 = w[1], w2 = w[2], w3 = w[3], w4 = w[4],
          w5 = w[5], w6 = w[6], w7 = w[7], w8 = w[8];
    float bb = dw1b[e * 3 + c];
    float acc[8];
    #pragma unroll
    for (int ox = 0; ox < 8; ++ox) acc[ox] = bb;
    #pragma unroll
    for (int ky = 0; ky < 3; ++ky) {
      int iy = oy * 2 - 1 + ky;
      if ((unsigned)iy > 15u) continue;
      const unsigned short* rp = base + iy * 16;
      short8 lo = *reinterpret_cast<const short8*>(rp);
      short8 hi = *reinterpret_cast<const short8*>(rp + 8);
      float r[16];
      #pragma unroll
      for (int p = 0; p < 8; ++p) {
        r[p] = bf2f((unsigned short)lo[p]);
        r[8 + p] = bf2f((unsigned short)hi[p]);
      }
      float wk0 = (ky == 0) ? w0 : (ky == 1) ? w3 : w6;
      float wk1 = (ky == 0) ? w1 : (ky == 1) ? w4 : w7;
      float wk2 = (ky == 0) ? w2 : (ky == 1) ? w5 : w8;
      #pragma unroll
      for (int ox = 0; ox < 8; ++ox) {
        int ix0 = ox * 2 - 1;
        if (ix0 >= 0) acc[ox] += wk0 * r[ix0];
        acc[ox] += wk1 * r[ix0 + 1];
        acc[ox] += wk2 * r[ix0 + 2];
      }
    }
    float* sa = s_a + en * 192 + c * 64 + oy * 8;
    #pragma unroll
    for (int ox = 0; ox < 8; ++ox) sa[ox] = fmaxf(acc[ox], 0.f);
  }
  __syncthreads();

  // ---- pw1 (3->64) + dw2 (8->4) fused in registers; thread=(entry,ch) ----
  {
    int en = tid >> 6, ch = tid & 63;
    const float* w1 = pw1w + (e * 64 + ch) * 3;
    float w10 = w1[0], w11 = w1[1], w12 = w1[2];
    float b1 = pw1b[e * 64 + ch];
    float v[64];
    const float* sa = s_a + en * 192;
    #pragma unroll
    for (int p = 0; p < 64; p += 4) {
      float4 a0 = *reinterpret_cast<const float4*>(sa + p);
      float4 a1 = *reinterpret_cast<const float4*>(sa + 64 + p);
      float4 a2 = *reinterpret_cast<const float4*>(sa + 128 + p);
      v[p + 0] = fmaxf(b1 + w10 * a0.x + w11 * a1.x + w12 * a2.x, 0.f);
      v[p + 1] = fmaxf(b1 + w10 * a0.y + w11 * a1.y + w12 * a2.y, 0.f);
      v[p + 2] = fmaxf(b1 + w10 * a0.z + w11 * a1.z + w12 * a2.z, 0.f);
      v[p + 3] = fmaxf(b1 + w10 * a0.w + w11 * a1.w + w12 * a2.w, 0.f);
    }
    const float* w2d = dw2w + (e * 64 + ch) * 9;
    float b2 = dw2b[e * 64 + ch];
    #pragma unroll
    for (int oy = 0; oy < 4; ++oy) {
      #pragma unroll
      for (int ox = 0; ox < 4; ++ox) {
        float acc = b2;
        #pragma unroll
        for (int ky = 0; ky < 3; ++ky) {
          int iy = oy * 2 - 1 + ky; if ((unsigned)iy > 7u) continue;
          #pragma unroll
          for (int kx = 0; kx < 3; ++kx) {
            int ix = ox * 2 - 1 + kx; if ((unsigned)ix > 7u) continue;
            acc += w2d[ky * 3 + kx] * v[iy * 8 + ix];
          }
        }
        int row = en * 16 + oy * 4 + ox;
        int elem = ch ^ ((row & 7) << 3);
        s_c[row * 64 + elem] = f2bf(fmaxf(acc, 0.f));
      }
    }
  }
  __syncthreads();

  // ---- pw2 via MFMA: M=128(o), N=128(pos=en*16+p), K=64 ----
  {
    int wid = tid >> 6, lane = tid & 63, lr = lane & 15, kg = lane >> 4;
    f32x4 acc[8] = {};
    #pragma unroll
    for (int ks = 0; ks < 2; ++ks) {
      int o = wid * 16 + lr;
      short8 a = *reinterpret_cast<const short8*>(w2bf + ((size_t)e * 128 + o) * 64 + ks * 32 + kg * 8);
      #pragma unroll
      for (int nt = 0; nt < 8; ++nt) {
        int row = nt * 16 + lr;
        int k0 = (ks * 32 + kg * 8) ^ ((row & 7) << 3);
        short8 b = *reinterpret_cast<const short8*>(s_c + row * 64 + k0);
        acc[nt] = __builtin_amdgcn_mfma_f32_16x16x32_bf16(a, b, acc[nt], 0, 0, 0);
      }
    }
    int o0 = wid * 16 + kg * 4;
    float4 bb = *reinterpret_cast<const float4*>(pw2b + e * 128 + o0);
    #pragma unroll
    for (int nt = 0; nt < 8; ++nt) {
      ushort4 pk;
      pk.x = f2bf(fmaxf(acc[nt][0] + bb.x, 0.f));
      pk.y = f2bf(fmaxf(acc[nt][1] + bb.y, 0.f));
      pk.z = f2bf(fmaxf(acc[nt][2] + bb.z, 0.f));
      pk.w = f2bf(fmaxf(acc[nt][3] + bb.w, 0.f));
      *reinterpret_cast<ushort4*>(s_d + nt * 2048 + lr * 128 + (o0 ^ (lr << 3))) = pk;
    }
  }
  __syncthreads();

  // ---- dw3: thread=(en, 2-ch group); b32 vector LDS reads/stores ----
  {
    int en = tid >> 6, chg = tid & 63;
    int ch0 = chg * 2;
    float in0[16], in1[16];
    #pragma unroll
    for (int q = 0; q < 16; ++q) {
      ushort2 pr = *reinterpret_cast<const ushort2*>(s_d + en * 2048 + q * 128 + (ch0 ^ (q << 3)));
      in0[q] = bf2f(pr.x); in1[q] = bf2f(pr.y);
    }
    const float* wd = dw3w + (e * 128 + ch0) * 9;
    float b30 = dw3b[e * 128 + ch0], b31 = dw3b[e * 128 + ch0 + 1];
    #pragma unroll
    for (int oy = 0; oy < 2; ++oy) {
      #pragma unroll
      for (int ox = 0; ox < 2; ++ox) {
        float a0 = b30, a1 = b31;
        #pragma unroll
        for (int ky = 0; ky < 3; ++ky) {
          int iy = oy * 2 - 1 + ky; if ((unsigned)iy > 3u) continue;
          #pragma unroll
          for (int kx = 0; kx < 3; ++kx) {
            int ix = ox * 2 - 1 + kx; if ((unsigned)ix > 3u) continue;
            a0 += wd[ky * 3 + kx] * in0[iy * 4 + ix];
            a1 += wd[9 + ky * 3 + kx] * in1[iy * 4 + ix];
          }
        }
        int row = en * 4 + oy * 2 + ox;
        int elem = ch0 ^ ((row & 7) << 3);
        ushort2 pk;
        pk.x = f2bf(fmaxf(a0, 0.f));
        pk.y = f2bf(fmaxf(a1, 0.f));
        *reinterpret_cast<ushort2*>(s_e3 + row * 128 + elem) = pk;
      }
    }
  }
  __syncthreads();

  // ---- pw3 via MFMA: M=256(o), N=32(pos=en*4+q), K=128; relu+meanpool ----
  {
    int wid = tid >> 6, lane = tid & 63, lr = lane & 15, kg = lane >> 4;
    f32x4 acc3[2][2] = {};
    #pragma unroll
    for (int ks = 0; ks < 4; ++ks) {
      short8 b[2];
      #pragma unroll
      for (int nb = 0; nb < 2; ++nb) {
        int row16 = nb * 16 + lr;
        int k0 = (ks * 32 + kg * 8) ^ ((row16 & 7) << 3);
        b[nb] = *reinterpret_cast<const short8*>(s_e3 + row16 * 128 + k0);
      }
      #pragma unroll
      for (int m = 0; m < 2; ++m) {
        int o = (wid * 2 + m) * 16 + lr;
        short8 a = *reinterpret_cast<const short8*>(w3bf + ((size_t)e * 256 + o) * 128 + ks * 32 + kg * 8);
        #pragma unroll
        for (int nb = 0; nb < 2; ++nb)
          acc3[m][nb] = __builtin_amdgcn_mfma_f32_16x16x32_bf16(a, b[nb], acc3[m][nb], 0, 0, 0);
      }
    }
    #pragma unroll
    for (int nb = 0; nb < 2; ++nb) {
      int en = nb * 4 + (lr >> 2);
      int ent = s_ent[en];
      int ok = s_val[en] && ((lr & 3) == 0);
      #pragma unroll
      for (int m = 0; m < 2; ++m) {
        #pragma unroll
        for (int r = 0; r < 4; ++r) {
          int o = (wid * 2 + m) * 16 + kg * 4 + r;
          float val = fmaxf(acc3[m][nb][r] + pw3b[e * 256 + o], 0.f);
          val += __shfl_xor(val, 1, 64);
          val += __shfl_xor(val, 2, 64);
          if (ok) featsbf[(size_t)ent * 256 + o] = f2bf(val * 0.25f);
        }
      }
    }
  }
}

// ---------------- fused combine+emb GEMM via MFMA --------------------------
// 128 threads / 2 waves; 32 entries x 128 outs per block (oh picks o-half).
// Writes emb2 as bf16 (halves traffic; sum re-adds in fp32).
__global__ __launch_bounds__(128) void combine4(
    const unsigned short* __restrict__ flatbf,   // [8192][768]
    const unsigned short* __restrict__ featsbf,  // [16384][256]
    const unsigned short* __restrict__ Wf,       // [8][256][1024]
    const float* __restrict__ cb,                // [8][256]
    const float* __restrict__ gval, const int* __restrict__ bin,
    const int* __restrict__ cnt, unsigned short* __restrict__ emb2)
{
  int e = blockIdx.x >> 1, oh = blockIdx.x & 1;
  int n = cnt[e];
  int chunk = blockIdx.y;
  if (chunk * 32 >= n) return;
  int tid = threadIdx.x;
  int wv = tid >> 6, lane = tid & 63;
  __shared__ int s_ent[32];
  __shared__ float s_g[32];
  __shared__ int s_ok[32];
  if (tid < 32) {
    int idx = chunk * 32 + tid;
    if (idx < n) {
      int ent = bin[e * 8192 + idx];
      s_ent[tid] = ent; s_g[tid] = gval[ent]; s_ok[tid] = 1;
    } else {
      int ent0 = bin[e * 8192];
      s_ent[tid] = ent0; s_g[tid] = 0.f; s_ok[tid] = 0;
    }
  }
  __syncthreads();

  int lr = lane & 15, kg = lane >> 4;
  int obase = oh * 128 + wv * 64;
  const unsigned short* af[2];
  #pragma unroll
  for (int i = 0; i < 2; ++i)
    af[i] = flatbf + (size_t)(s_ent[i * 16 + lr] >> 1) * 768 + kg * 8;
  const unsigned short* bp = Wf + ((size_t)e * 256 + obase + lr) * 1024 + kg * 8;

  f32x4 acc[2][4] = {};

  // K phase 1: flat path, K=768
  for (int kb = 0; kb < 768; kb += 32) {
    short8 a[2], b[4];
    #pragma unroll
    for (int i = 0; i < 2; ++i) a[i] = *reinterpret_cast<const short8*>(af[i] + kb);
    #pragma unroll
    for (int j = 0; j < 4; ++j) b[j] = *reinterpret_cast<const short8*>(bp + j * 16 * 1024 + kb);
    #pragma unroll
    for (int i = 0; i < 2; ++i)
      #pragma unroll
      for (int j = 0; j < 4; ++j)
        acc[i][j] = __builtin_amdgcn_mfma_f32_16x16x32_bf16(a[i], b[j], acc[i][j], 0, 0, 0);
  }

  // K phase 2: feats path, K=256 (Wf cols 768..1023)
  const unsigned short* at[2];
  #pragma unroll
  for (int i = 0; i < 2; ++i)
    at[i] = featsbf + (size_t)s_ent[i * 16 + lr] * 256 + kg * 8;
  for (int kb = 0; kb < 256; kb += 32) {
    short8 a[2], b[4];
    #pragma unroll
    for (int i = 0; i < 2; ++i) a[i] = *reinterpret_cast<const short8*>(at[i] + kb);
    #pragma unroll
    for (int j = 0; j < 4; ++j) b[j] = *reinterpret_cast<const short8*>(bp + j * 16 * 1024 + 768 + kb);
    #pragma unroll
    for (int i = 0; i < 2; ++i)
      #pragma unroll
      for (int j = 0; j < 4; ++j)
        acc[i][j] = __builtin_amdgcn_mfma_f32_16x16x32_bf16(a[i], b[j], acc[i][j], 0, 0, 0);
  }

  // D: col(lane&15) = o within b-tile j; row(kg*4+r) = entry within m-tile i
  #pragma unroll
  for (int j = 0; j < 4; ++j) {
    int o = obase + j * 16 + lr;
    float cbo = cb[e * 256 + o];
    #pragma unroll
    for (int i = 0; i < 2; ++i) {
      #pragma unroll
      for (int r = 0; r < 4; ++r) {
        int m = i * 16 + kg * 4 + r;
        if (s_ok[m])
          emb2[(size_t)s_ent[m] * 256 + o] = f2bf(s_g[m] * (acc[i][j][r] + cbo));
      }
    }
  }
}

// ---------------- sum two entry rows per token + transposed write ----------
// out[bi, o, nn] = emb2[t*2][o] + emb2[t*2+1][o],  t = bi*256+nn
__global__ __launch_bounds__(256) void sum_kernel(const unsigned short* __restrict__ emb2,
                                                  float* __restrict__ out)
{
  __shared__ float s_sum[32][257];
  int tt = blockIdx.x;          // 32-token group
  int tid = threadIdx.x;
  int t0 = tt * 32;
  for (int s = 0; s < 32; ++s) {
    int t = t0 + s;
    float a = bf2f(emb2[((size_t)t * 2) * 256 + tid]);
    float b = bf2f(emb2[((size_t)t * 2 + 1) * 256 + tid]);
    s_sum[s][tid] = a + b;
  }
  __syncthreads();
  int bi = t0 >> 8, nn0 = t0 & 255;
  int s = tid & 31, oh = tid >> 5;   // 8 o-groups x 32 token-lanes
  for (int ob = 0; ob < 32; ++ob) {
    int o = ob * 8 + oh;
    out[(((size_t)bi * 256 + o) << 8) + nn0 + s] = s_sum[s][o];
  }
}

extern "C" void kernel_launch(void* const* d_in, const int* in_sizes, int n_in,
                              void* d_out, int out_size, void* d_ws, size_t ws_size,
                              hipStream_t stream)
{
  (void)in_sizes; (void)n_in; (void)out_size; (void)ws_size;
  const float* x    = (const float*)d_in[0];
  const float* gw   = (const float*)d_in[1];
  const float* gb   = (const float*)d_in[2];
  const float* dw1w = (const float*)d_in[3];
  const float* dw1b = (const float*)d_in[4];
  const float* pw1w = (const float*)d_in[5];
  const float* pw1b = (const float*)d_in[6];
  const float* dw2w = (const float*)d_in[7];
  const float* dw2b = (const float*)d_in[8];
  const float* pw2w = (const float*)d_in[9];
  const float* pw2b = (const float*)d_in[10];
  const float* dw3w = (const float*)d_in[11];
  const float* dw3b = (const float*)d_in[12];
  const float* pw3w = (const float*)d_in[13];
  const float* pw3b = (const float*)d_in[14];
  const float* thw  = (const float*)d_in[15];
  const float* thb  = (const float*)d_in[16];
  const float* resw = (const float*)d_in[17];
  const float* resb = (const float*)d_in[18];
  const float* tew  = (const float*)d_in[19];
  const float* teb  = (const float*)d_in[20];

  float* ws    = (float*)d_ws;
  unsigned short* emb2  = (unsigned short*)ws;                 // 16384*256 bf16 (8 MB)
  unsigned short* w2bf  = (unsigned short*)(ws + 6291456);     // 65536 us
  unsigned short* w3bf  = (unsigned short*)(ws + 6324224);     // 262144 us
  unsigned short* tebf  = (unsigned short*)(ws + 6455296);     // 196608 us
  unsigned short* Wf    = (unsigned short*)(ws + 6553600);     // 2097152 us (4 MB)
  float* cb    = ws + 7602176;                                 // 2048 f
  float* probs = ws + 8000000;                                 // 65536 f
  float* gval  = ws + 16777216;           // 16384 f
  int*   gidx  = (int*)(ws + 16793600);   // 16384 i
  float* aux   = ws + 16809984;           // 256 f
  int*   cnt   = (int*)(ws + 16810240);   // 8 i
  int*   bin   = (int*)(ws + 16810248);   // 65536 i
  unsigned short* flatbf  = (unsigned short*)(ws + 16875784);  // 8192*768 us
  unsigned short* featsbf = (unsigned short*)(ws + 20021512);  // 16384*256 us
  float* out   = (float*)d_out;

  hipMemsetAsync(aux, 0, 264 * sizeof(float), stream);   // aux(256) + cnt(8)

  patchgate_kernel<<<8192, 256, 0, stream>>>(x, gw, gb, flatbf, gidx, gval, probs);
  auxred_kernel<<<32, 256, 0, stream>>>(probs, gidx, aux);
  bin_kernel<<<64, 256, 0, stream>>>(gidx, cnt, bin);
  laux_kernel<<<1, 64, 0, stream>>>(aux, out);
  f2bf3_kernel<<<512, 256, 0, stream>>>(pw2w, pw3w, tew, w2bf, w3bf, tebf);

  dim3 wg(16, 4, 8);
  wfuse_kernel<<<wg, 256, 0, stream>>>(tebf, resw, thw, Wf);
  dim3 cbg(8, 16);
  cbias_kernel<<<cbg, 256, 0, stream>>>(tew, thb, resb, teb, cb);

  dim3 cnng(8, 1024);
  cnn_mfma<<<cnng, 512, 0, stream>>>(flatbf, bin, cnt, dw1w, dw1b, pw1w, pw1b,
                                     dw2w, dw2b, w2bf, pw2b, dw3w, dw3b,
                                     w3bf, pw3b, featsbf);

  dim3 cg(16, 256);
  combine4<<<cg, 128, 0, stream>>>(flatbf, featsbf, Wf, cb, gval, bin, cnt, emb2);
  sum_kernel<<<256, 256, 0, stream>>>(emb2, out);
}

// Round 19
// 260.404 us; speedup vs baseline: 1.0495x; 1.0033x over previous
//
#include <hip/hip_runtime.h>

#define NTOK 8192

typedef __attribute__((ext_vector_type(8))) short short8;
typedef __attribute__((ext_vector_type(4))) float f32x4;

__device__ __forceinline__ unsigned short f2bf(float f) {
  unsigned u = __float_as_uint(f);
  u += 0x7FFFu + ((u >> 16) & 1u);
  return (unsigned short)(u >> 16);
}
__device__ __forceinline__ float bf2f(unsigned short u) {
  return __uint_as_float(((unsigned)u) << 16);
}

// ---------------- fused patchify + gate: one block per token ---------------
__global__ __launch_bounds__(256) void patchgate_kernel(
    const float* __restrict__ x, const float* __restrict__ gw,
    const float* __restrict__ gb, unsigned short* __restrict__ flatbf,
    int* __restrict__ gidx, float* __restrict__ gval,
    float* __restrict__ probs)
{
  int t = blockIdx.x;          // 0..8191
  int tid = threadIdx.x;
  int b = t >> 8, ph = (t >> 4) & 15, pw = t & 15;
  const float* xb = x + (size_t)b * 3 * 256 * 256;
  float acc[8];
  #pragma unroll
  for (int e = 0; e < 8; ++e) acc[e] = 0.f;
  #pragma unroll
  for (int r = 0; r < 3; ++r) {
    int d = r * 256 + tid;
    int c = d >> 8, i = (d >> 4) & 15, j = d & 15;
    float v = xb[((size_t)c * 256 + ph * 16 + i) * 256 + pw * 16 + j];
    flatbf[(size_t)t * 768 + d] = f2bf(v);
    const float* g = gw + d * 8;
    #pragma unroll
    for (int e = 0; e < 8; ++e) acc[e] += v * g[e];
  }
  #pragma unroll
  for (int e = 0; e < 8; ++e) {
    #pragma unroll
    for (int off = 32; off > 0; off >>= 1)
      acc[e] += __shfl_down(acc[e], off, 64);
  }
  __shared__ float s_red[4][8];
  int wid = tid >> 6, lane = tid & 63;
  if (lane == 0) {
    #pragma unroll
    for (int e = 0; e < 8; ++e) s_red[wid][e] = acc[e];
  }
  __syncthreads();
  if (tid == 0) {
    float lg[8];
    #pragma unroll
    for (int e = 0; e < 8; ++e)
      lg[e] = s_red[0][e] + s_red[1][e] + s_red[2][e] + s_red[3][e] + gb[e];
    int i0 = 0; float v0 = lg[0];
    #pragma unroll
    for (int e = 1; e < 8; ++e) if (lg[e] > v0) { v0 = lg[e]; i0 = e; }
    int i1 = -1; float v1 = -1e30f;
    #pragma unroll
    for (int e = 0; e < 8; ++e) { if (e == i0) continue; if (lg[e] > v1) { v1 = lg[e]; i1 = e; } }
    float e1 = __expf(v1 - v0);
    float s0 = 1.f / (1.f + e1);
    float s1 = e1 * s0;
    gidx[t * 2] = i0; gidx[t * 2 + 1] = i1;
    gval[t * 2] = s0; gval[t * 2 + 1] = s1;
    float sum = 0.f, p[8];
    #pragma unroll
    for (int e = 0; e < 8; ++e) { p[e] = __expf(lg[e] - v0); sum += p[e]; }
    float inv = 1.f / sum;
    #pragma unroll
    for (int e = 0; e < 8; ++e) probs[t * 8 + e] = p[e] * inv;
  }
}

// ---------------- fused aux reduction + expert binning ---------------------
// thread t: me/ce stats for token t, and bins entries 2t, 2t+1.
__global__ __launch_bounds__(256) void auxbin_kernel(const float* __restrict__ probs,
                                                     const int* __restrict__ gidx,
                                                     float* __restrict__ aux,
                                                     int* __restrict__ cnt,
                                                     int* __restrict__ bin)
{
  __shared__ float s_me[8];
  __shared__ float s_ce[8];
  int tid = threadIdx.x, lane = tid & 63;
  if (tid < 8) { s_me[tid] = 0.f; s_ce[tid] = 0.f; }
  __syncthreads();
  int t = blockIdx.x * 256 + tid;
  float p[8];
  #pragma unroll
  for (int e = 0; e < 8; ++e) p[e] = probs[t * 8 + e];
  int e0 = gidx[t * 2], e1 = gidx[t * 2 + 1];
  // bin the two entries of this token
  {
    int pos0 = atomicAdd(&cnt[e0], 1);
    bin[e0 * 8192 + pos0] = t * 2;
    int pos1 = atomicAdd(&cnt[e1], 1);
    bin[e1 * 8192 + pos1] = t * 2 + 1;
  }
  #pragma unroll
  for (int e = 0; e < 8; ++e) {
    #pragma unroll
    for (int off = 32; off > 0; off >>= 1)
      p[e] += __shfl_down(p[e], off, 64);
  }
  if (lane == 0) {
    #pragma unroll
    for (int e = 0; e < 8; ++e) atomicAdd(&s_me[e], p[e]);
  }
  #pragma unroll
  for (int e = 0; e < 8; ++e) {
    unsigned long long m = __ballot(e0 == e);
    if (lane == 0) atomicAdd(&s_ce[e], (float)__popcll(m));
  }
  __syncthreads();
  if (tid < 8) {
    atomicAdd(&aux[tid * 16], s_ce[tid]);            // ce
    atomicAdd(&aux[128 + tid * 16], s_me[tid]);      // me
  }
}

// ---------------- prep: f2bf of pw2w/pw3w/tew (blk<512) + cbias (blk>=512) -
__global__ __launch_bounds__(256) void prep_kernel(
    const float* __restrict__ pw2w, const float* __restrict__ pw3w,
    const float* __restrict__ tew,
    unsigned short* __restrict__ w2bf, unsigned short* __restrict__ w3bf,
    unsigned short* __restrict__ tebf,
    const float* __restrict__ thb, const float* __restrict__ resb,
    const float* __restrict__ teb, float* __restrict__ cb)
{
  int blk = blockIdx.x;
  int tid = threadIdx.x;
  if (blk < 640 - 128) {
    const float* in; unsigned short* out; size_t base;
    if (blk < 64)       { in = pw2w; out = w2bf; base = (size_t)blk * 1024; }
    else if (blk < 320) { in = pw3w; out = w3bf; base = (size_t)(blk - 64) * 1024; }
    else                { in = tew;  out = tebf; base = (size_t)(blk - 320) * 1024; }
    size_t i = base + tid * 4;
    float4 v = *reinterpret_cast<const float4*>(in + i);
    ushort4 o;
    o.x = f2bf(v.x); o.y = f2bf(v.y); o.z = f2bf(v.z); o.w = f2bf(v.w);
    *reinterpret_cast<ushort4*>(out + i) = o;
  } else {
    int idx = blk - 512;               // 0..127
    int e = idx >> 4, oc = idx & 15;
    int o = oc * 16 + (tid >> 4), g = tid & 15;
    float s = 0.f;
    for (int j = 0; j < 12; ++j) {
      int d = j * 64 + g * 4;
      float4 t4 = *reinterpret_cast<const float4*>(tew + (size_t)o * 768 + d);
      float4 b1 = *reinterpret_cast<const float4*>(thb + (size_t)e * 768 + d);
      float4 b2 = *reinterpret_cast<const float4*>(resb + (size_t)e * 768 + d);
      s += t4.x * (b1.x + b2.x) + t4.y * (b1.y + b2.y) + t4.z * (b1.z + b2.z) + t4.w * (b1.w + b2.w);
    }
    #pragma unroll
    for (int m = 8; m > 0; m >>= 1) s += __shfl_xor(s, m, 64);
    if (g == 0) cb[e * 256 + o] = s + teb[o];
  }
}

// ---------------- Wfused[e][o][k] = sum_d te[o,d] * M_e[d,k] ---------------
__global__ __launch_bounds__(256) void wfuse_kernel(const unsigned short* __restrict__ tebf, // [256][768]
                                                    const float* __restrict__ resw,
                                                    const float* __restrict__ thw,
                                                    unsigned short* __restrict__ Wf)
{
  int kt = blockIdx.x, oq = blockIdx.y, e = blockIdx.z;
  const float* src; int ld, kcol0;
  if (kt < 12) { src = resw + (size_t)e * 768 * 768; ld = 768; kcol0 = kt * 64; }
  else         { src = thw + (size_t)e * 768 * 256;  ld = 256; kcol0 = (kt - 12) * 64; }

  __shared__ unsigned short s_t[64 * 64];  // [k][d] XOR-swizzled
  int tid = threadIdx.x;
  int wid = tid >> 6, lane = tid & 63, lr = lane & 15, kg = lane >> 4;

  f32x4 acc[4] = {};
  // ap includes the per-lane kg*8 k-group offset; d-loop adds only d0+st*32.
  const unsigned short* ap = tebf + (size_t)(oq * 64 + wid * 16 + lr) * 768 + kg * 8;

  for (int d0 = 0; d0 < 768; d0 += 64) {
    #pragma unroll
    for (int p = 0; p < 4; ++p) {
      int dl = p * 16 + (tid >> 4);
      int f4 = tid & 15;
      float4 v = *reinterpret_cast<const float4*>(src + (size_t)(d0 + dl) * ld + kcol0 + f4 * 4);
      #pragma unroll
      for (int j = 0; j < 4; ++j) {
        int kk = f4 * 4 + j;
        float vj = (j == 0) ? v.x : (j == 1) ? v.y : (j == 2) ? v.z : v.w;
        s_t[kk * 64 + (dl ^ ((kk & 7) << 3))] = f2bf(vj);
      }
    }
    __syncthreads();
    #pragma unroll
    for (int st = 0; st < 2; ++st) {
      int doff = st * 32 + kg * 8;
      short8 a = *reinterpret_cast<const short8*>(ap + d0 + st * 32);
      #pragma unroll
      for (int nt = 0; nt < 4; ++nt) {
        int k16 = nt * 16 + lr;
        short8 b = *reinterpret_cast<const short8*>(s_t + k16 * 64 + (doff ^ ((k16 & 7) << 3)));
        acc[nt] = __builtin_amdgcn_mfma_f32_16x16x32_bf16(a, b, acc[nt], 0, 0, 0);
      }
    }
    __syncthreads();
  }

  #pragma unroll
  for (int nt = 0; nt < 4; ++nt) {
    #pragma unroll
    for (int r = 0; r < 4; ++r) {
      int o = oq * 64 + wid * 16 + kg * 4 + r;
      int k = kt * 64 + nt * 16 + lr;
      Wf[((size_t)e * 256 + o) * 1024 + k] = f2bf(acc[nt][r]);
    }
  }
}

// ---------------- expert CNN tower via MFMA: 8 entries of one expert/block -
// dw1 reads flatbf directly from global (rows L2-hot).
__global__ __launch_bounds__(512) void cnn_mfma(
    const unsigned short* __restrict__ flatbf, const int* __restrict__ bin,
    const int* __restrict__ cnt,
    const float* __restrict__ dw1w, const float* __restrict__ dw1b,
    const float* __restrict__ pw1w, const float* __restrict__ pw1b,
    const float* __restrict__ dw2w, const float* __restrict__ dw2b,
    const unsigned short* __restrict__ w2bf, const float* __restrict__ pw2b,
    const float* __restrict__ dw3w, const float* __restrict__ dw3b,
    const unsigned short* __restrict__ w3bf, const float* __restrict__ pw3b,
    unsigned short* __restrict__ featsbf)
{
  int e = blockIdx.x;
  int n = cnt[e];
  int chunk = blockIdx.y;
  if (chunk * 8 >= n) return;

  __shared__ __align__(16) char smem[49280];
  float*          s_a  = (float*)smem;                     // 6144 B  [en][3][8][8]
  unsigned short* s_d  = (unsigned short*)smem;            // 32768 B [en][16pos][128ch swz] (over s_a)
  unsigned short* s_c  = (unsigned short*)(smem + 32768);  // 16384 B [row=en*16+pos][64ch swz]
  unsigned short* s_e3 = (unsigned short*)(smem + 32768);  // 8192 B  [row=en*4+q][128ch swz] (over s_c)
  int* s_ent = (int*)(smem + 49152);
  int* s_val = s_ent + 8;

  int tid = threadIdx.x;
  if (tid < 8) {
    int idx = chunk * 8 + tid;
    int ok = idx < n;
    s_ent[tid] = bin[e * 8192 + (ok ? idx : 0)];
    s_val[tid] = ok;
  }
  __syncthreads();

  // ---- dw1: thread=(en,c,oy) computes 8-wide output row; global vec reads -
  if (tid < 192) {
    int en = tid / 24, rem = tid % 24;
    int c = rem >> 3, oy = rem & 7;
    int tok = s_ent[en] >> 1;
    const unsigned short* base = flatbf + (size_t)tok * 768 + c * 256;
    const float* w = dw1w + (e * 3 + c) * 9;
    float w0 = w[0], w1 = w[1], w2 = w[2], w3 = w[3], w4 = w[4],
          w5 = w[5], w6 = w[6], w7 = w[7], w8 = w[8];
    float bb = dw1b[e * 3 + c];
    float acc[8];
    #pragma unroll
    for (int ox = 0; ox < 8; ++ox) acc[ox] = bb;
    #pragma unroll
    for (int ky = 0; ky < 3; ++ky) {
      int iy = oy * 2 - 1 + ky;
      if ((unsigned)iy > 15u) continue;
      const unsigned short* rp = base + iy * 16;
      short8 lo = *reinterpret_cast<const short8*>(rp);
      short8 hi = *reinterpret_cast<const short8*>(rp + 8);
      float r[16];
      #pragma unroll
      for (int p = 0; p < 8; ++p) {
        r[p] = bf2f((unsigned short)lo[p]);
        r[8 + p] = bf2f((unsigned short)hi[p]);
      }
      float wk0 = (ky == 0) ? w0 : (ky == 1) ? w3 : w6;
      float wk1 = (ky == 0) ? w1 : (ky == 1) ? w4 : w7;
      float wk2 = (ky == 0) ? w2 : (ky == 1) ? w5 : w8;
      #pragma unroll
      for (int ox = 0; ox < 8; ++ox) {
        int ix0 = ox * 2 - 1;
        if (ix0 >= 0) acc[ox] += wk0 * r[ix0];
        acc[ox] += wk1 * r[ix0 + 1];
        acc[ox] += wk2 * r[ix0 + 2];
      }
    }
    float* sa = s_a + en * 192 + c * 64 + oy * 8;
    #pragma unroll
    for (int ox = 0; ox < 8; ++ox) sa[ox] = fmaxf(acc[ox], 0.f);
  }
  __syncthreads();

  // ---- pw1 (3->64) + dw2 (8->4) fused in registers; thread=(entry,ch) ----
  {
    int en = tid >> 6, ch = tid & 63;
    const float* w1 = pw1w + (e * 64 + ch) * 3;
    float w10 = w1[0], w11 = w1[1], w12 = w1[2];
    float b1 = pw1b[e * 64 + ch];
    float v[64];
    const float* sa = s_a + en * 192;
    #pragma unroll
    for (int p = 0; p < 64; p += 4) {
      float4 a0 = *reinterpret_cast<const float4*>(sa + p);
      float4 a1 = *reinterpret_cast<const float4*>(sa + 64 + p);
      float4 a2 = *reinterpret_cast<const float4*>(sa + 128 + p);
      v[p + 0] = fmaxf(b1 + w10 * a0.x + w11 * a1.x + w12 * a2.x, 0.f);
      v[p + 1] = fmaxf(b1 + w10 * a0.y + w11 * a1.y + w12 * a2.y, 0.f);
      v[p + 2] = fmaxf(b1 + w10 * a0.z + w11 * a1.z + w12 * a2.z, 0.f);
      v[p + 3] = fmaxf(b1 + w10 * a0.w + w11 * a1.w + w12 * a2.w, 0.f);
    }
    const float* w2d = dw2w + (e * 64 + ch) * 9;
    float b2 = dw2b[e * 64 + ch];
    #pragma unroll
    for (int oy = 0; oy < 4; ++oy) {
      #pragma unroll
      for (int ox = 0; ox < 4; ++ox) {
        float acc = b2;
        #pragma unroll
        for (int ky = 0; ky < 3; ++ky) {
          int iy = oy * 2 - 1 + ky; if ((unsigned)iy > 7u) continue;
          #pragma unroll
          for (int kx = 0; kx < 3; ++kx) {
            int ix = ox * 2 - 1 + kx; if ((unsigned)ix > 7u) continue;
            acc += w2d[ky * 3 + kx] * v[iy * 8 + ix];
          }
        }
        int row = en * 16 + oy * 4 + ox;
        int elem = ch ^ ((row & 7) << 3);
        s_c[row * 64 + elem] = f2bf(fmaxf(acc, 0.f));
      }
    }
  }
  __syncthreads();

  // ---- pw2 via MFMA: M=128(o), N=128(pos=en*16+p), K=64 ----
  {
    int wid = tid >> 6, lane = tid & 63, lr = lane & 15, kg = lane >> 4;
    f32x4 acc[8] = {};
    #pragma unroll
    for (int ks = 0; ks < 2; ++ks) {
      int o = wid * 16 + lr;
      short8 a = *reinterpret_cast<const short8*>(w2bf + ((size_t)e * 128 + o) * 64 + ks * 32 + kg * 8);
      #pragma unroll
      for (int nt = 0; nt < 8; ++nt) {
        int row = nt * 16 + lr;
        int k0 = (ks * 32 + kg * 8) ^ ((row & 7) << 3);
        short8 b = *reinterpret_cast<const short8*>(s_c + row * 64 + k0);
        acc[nt] = __builtin_amdgcn_mfma_f32_16x16x32_bf16(a, b, acc[nt], 0, 0, 0);
      }
    }
    int o0 = wid * 16 + kg * 4;
    float4 bb = *reinterpret_cast<const float4*>(pw2b + e * 128 + o0);
    #pragma unroll
    for (int nt = 0; nt < 8; ++nt) {
      ushort4 pk;
      pk.x = f2bf(fmaxf(acc[nt][0] + bb.x, 0.f));
      pk.y = f2bf(fmaxf(acc[nt][1] + bb.y, 0.f));
      pk.z = f2bf(fmaxf(acc[nt][2] + bb.z, 0.f));
      pk.w = f2bf(fmaxf(acc[nt][3] + bb.w, 0.f));
      *reinterpret_cast<ushort4*>(s_d + nt * 2048 + lr * 128 + (o0 ^ (lr << 3))) = pk;
    }
  }
  __syncthreads();

  // ---- dw3: thread=(en, 2-ch group); b32 vector LDS reads/stores ----
  {
    int en = tid >> 6, chg = tid & 63;
    int ch0 = chg * 2;
    float in0[16], in1[16];
    #pragma unroll
    for (int q = 0; q < 16; ++q) {
      ushort2 pr = *reinterpret_cast<const ushort2*>(s_d + en * 2048 + q * 128 + (ch0 ^ (q << 3)));
      in0[q] = bf2f(pr.x); in1[q] = bf2f(pr.y);
    }
    const float* wd = dw3w + (e * 128 + ch0) * 9;
    float b30 = dw3b[e * 128 + ch0], b31 = dw3b[e * 128 + ch0 + 1];
    #pragma unroll
    for (int oy = 0; oy < 2; ++oy) {
      #pragma unroll
      for (int ox = 0; ox < 2; ++ox) {
        float a0 = b30, a1 = b31;
        #pragma unroll
        for (int ky = 0; ky < 3; ++ky) {
          int iy = oy * 2 - 1 + ky; if ((unsigned)iy > 3u) continue;
          #pragma unroll
          for (int kx = 0; kx < 3; ++kx) {
            int ix = ox * 2 - 1 + kx; if ((unsigned)ix > 3u) continue;
            a0 += wd[ky * 3 + kx] * in0[iy * 4 + ix];
            a1 += wd[9 + ky * 3 + kx] * in1[iy * 4 + ix];
          }
        }
        int row = en * 4 + oy * 2 + ox;
        int elem = ch0 ^ ((row & 7) << 3);
        ushort2 pk;
        pk.x = f2bf(fmaxf(a0, 0.f));
        pk.y = f2bf(fmaxf(a1, 0.f));
        *reinterpret_cast<ushort2*>(s_e3 + row * 128 + elem) = pk;
      }
    }
  }
  __syncthreads();

  // ---- pw3 via MFMA: M=256(o), N=32(pos=en*4+q), K=128; relu+meanpool ----
  {
    int wid = tid >> 6, lane = tid & 63, lr = lane & 15, kg = lane >> 4;
    f32x4 acc3[2][2] = {};
    #pragma unroll
    for (int ks = 0; ks < 4; ++ks) {
      short8 b[2];
      #pragma unroll
      for (int nb = 0; nb < 2; ++nb) {
        int row16 = nb * 16 + lr;
        int k0 = (ks * 32 + kg * 8) ^ ((row16 & 7) << 3);
        b[nb] = *reinterpret_cast<const short8*>(s_e3 + row16 * 128 + k0);
      }
      #pragma unroll
      for (int m = 0; m < 2; ++m) {
        int o = (wid * 2 + m) * 16 + lr;
        short8 a = *reinterpret_cast<const short8*>(w3bf + ((size_t)e * 256 + o) * 128 + ks * 32 + kg * 8);
        #pragma unroll
        for (int nb = 0; nb < 2; ++nb)
          acc3[m][nb] = __builtin_amdgcn_mfma_f32_16x16x32_bf16(a, b[nb], acc3[m][nb], 0, 0, 0);
      }
    }
    #pragma unroll
    for (int nb = 0; nb < 2; ++nb) {
      int en = nb * 4 + (lr >> 2);
      int ent = s_ent[en];
      int ok = s_val[en] && ((lr & 3) == 0);
      #pragma unroll
      for (int m = 0; m < 2; ++m) {
        #pragma unroll
        for (int r = 0; r < 4; ++r) {
          int o = (wid * 2 + m) * 16 + kg * 4 + r;
          float val = fmaxf(acc3[m][nb][r] + pw3b[e * 256 + o], 0.f);
          val += __shfl_xor(val, 1, 64);
          val += __shfl_xor(val, 2, 64);
          if (ok) featsbf[(size_t)ent * 256 + o] = f2bf(val * 0.25f);
        }
      }
    }
  }
}

// ---------------- fused combine+emb GEMM via MFMA --------------------------
// 128 threads / 2 waves; 32 entries x 128 outs per block (oh picks o-half).
__global__ __launch_bounds__(128) void combine4(
    const unsigned short* __restrict__ flatbf,   // [8192][768]
    const unsigned short* __restrict__ featsbf,  // [16384][256]
    const unsigned short* __restrict__ Wf,       // [8][256][1024]
    const float* __restrict__ cb,                // [8][256]
    const float* __restrict__ gval, const int* __restrict__ bin,
    const int* __restrict__ cnt, unsigned short* __restrict__ emb2)
{
  int e = blockIdx.x >> 1, oh = blockIdx.x & 1;
  int n = cnt[e];
  int chunk = blockIdx.y;
  if (chunk * 32 >= n) return;
  int tid = threadIdx.x;
  int wv = tid >> 6, lane = tid & 63;
  __shared__ int s_ent[32];
  __shared__ float s_g[32];
  __shared__ int s_ok[32];
  if (tid < 32) {
    int idx = chunk * 32 + tid;
    if (idx < n) {
      int ent = bin[e * 8192 + idx];
      s_ent[tid] = ent; s_g[tid] = gval[ent]; s_ok[tid] = 1;
    } else {
      int ent0 = bin[e * 8192];
      s_ent[tid] = ent0; s_g[tid] = 0.f; s_ok[tid] = 0;
    }
  }
  __syncthreads();

  int lr = lane & 15, kg = lane >> 4;
  int obase = oh * 128 + wv * 64;
  const unsigned short* af[2];
  #pragma unroll
  for (int i = 0; i < 2; ++i)
    af[i] = flatbf + (size_t)(s_ent[i * 16 + lr] >> 1) * 768 + kg * 8;
  const unsigned short* bp = Wf + ((size_t)e * 256 + obase + lr) * 1024 + kg * 8;

  f32x4 acc[2][4] = {};

  // K phase 1: flat path, K=768
  for (int kb = 0; kb < 768; kb += 32) {
    short8 a[2], b[4];
    #pragma unroll
    for (int i = 0; i < 2; ++i) a[i] = *reinterpret_cast<const short8*>(af[i] + kb);
    #pragma unroll
    for (int j = 0; j < 4; ++j) b[j] = *reinterpret_cast<const short8*>(bp + j * 16 * 1024 + kb);
    #pragma unroll
    for (int i = 0; i < 2; ++i)
      #pragma unroll
      for (int j = 0; j < 4; ++j)
        acc[i][j] = __builtin_amdgcn_mfma_f32_16x16x32_bf16(a[i], b[j], acc[i][j], 0, 0, 0);
  }

  // K phase 2: feats path, K=256 (Wf cols 768..1023)
  const unsigned short* at[2];
  #pragma unroll
  for (int i = 0; i < 2; ++i)
    at[i] = featsbf + (size_t)s_ent[i * 16 + lr] * 256 + kg * 8;
  for (int kb = 0; kb < 256; kb += 32) {
    short8 a[2], b[4];
    #pragma unroll
    for (int i = 0; i < 2; ++i) a[i] = *reinterpret_cast<const short8*>(at[i] + kb);
    #pragma unroll
    for (int j = 0; j < 4; ++j) b[j] = *reinterpret_cast<const short8*>(bp + j * 16 * 1024 + 768 + kb);
    #pragma unroll
    for (int i = 0; i < 2; ++i)
      #pragma unroll
      for (int j = 0; j < 4; ++j)
        acc[i][j] = __builtin_amdgcn_mfma_f32_16x16x32_bf16(a[i], b[j], acc[i][j], 0, 0, 0);
  }

  // D: col(lane&15) = o within b-tile j; row(kg*4+r) = entry within m-tile i
  #pragma unroll
  for (int j = 0; j < 4; ++j) {
    int o = obase + j * 16 + lr;
    float cbo = cb[e * 256 + o];
    #pragma unroll
    for (int i = 0; i < 2; ++i) {
      #pragma unroll
      for (int r = 0; r < 4; ++r) {
        int m = i * 16 + kg * 4 + r;
        if (s_ok[m])
          emb2[(size_t)s_ent[m] * 256 + o] = f2bf(s_g[m] * (acc[i][j][r] + cbo));
      }
    }
  }
}

// ---------------- sum two entry rows per token + transposed write ----------
// out[bi, o, nn] = emb2[t*2][o] + emb2[t*2+1][o]; block 0 also writes l_aux.
__global__ __launch_bounds__(256) void sum_kernel(const unsigned short* __restrict__ emb2,
                                                  const float* __restrict__ aux,
                                                  float* __restrict__ out)
{
  if (blockIdx.x == 0 && threadIdx.x == 0) {
    float l = 0.f;
    for (int e = 0; e < 8; ++e)
      l += (aux[e * 16] / 8192.f) * (aux[128 + e * 16] / 8192.f);
    out[2097152] = 8.f * l;
  }
  __shared__ float s_sum[32][257];
  int tt = blockIdx.x;          // 32-token group
  int tid = threadIdx.x;
  int t0 = tt * 32;
  for (int s = 0; s < 32; ++s) {
    int t = t0 + s;
    float a = bf2f(emb2[((size_t)t * 2) * 256 + tid]);
    float b = bf2f(emb2[((size_t)t * 2 + 1) * 256 + tid]);
    s_sum[s][tid] = a + b;
  }
  __syncthreads();
  int bi = t0 >> 8, nn0 = t0 & 255;
  int s = tid & 31, oh = tid >> 5;   // 8 o-groups x 32 token-lanes
  for (int ob = 0; ob < 32; ++ob) {
    int o = ob * 8 + oh;
    out[(((size_t)bi * 256 + o) << 8) + nn0 + s] = s_sum[s][o];
  }
}

extern "C" void kernel_launch(void* const* d_in, const int* in_sizes, int n_in,
                              void* d_out, int out_size, void* d_ws, size_t ws_size,
                              hipStream_t stream)
{
  (void)in_sizes; (void)n_in; (void)out_size; (void)ws_size;
  const float* x    = (const float*)d_in[0];
  const float* gw   = (const float*)d_in[1];
  const float* gb   = (const float*)d_in[2];
  const float* dw1w = (const float*)d_in[3];
  const float* dw1b = (const float*)d_in[4];
  const float* pw1w = (const float*)d_in[5];
  const float* pw1b = (const float*)d_in[6];
  const float* dw2w = (const float*)d_in[7];
  const float* dw2b = (const float*)d_in[8];
  const float* pw2w = (const float*)d_in[9];
  const float* pw2b = (const float*)d_in[10];
  const float* dw3w = (const float*)d_in[11];
  const float* dw3b = (const float*)d_in[12];
  const float* pw3w = (const float*)d_in[13];
  const float* pw3b = (const float*)d_in[14];
  const float* thw  = (const float*)d_in[15];
  const float* thb  = (const float*)d_in[16];
  const float* resw = (const float*)d_in[17];
  const float* resb = (const float*)d_in[18];
  const float* tew  = (const float*)d_in[19];
  const float* teb  = (const float*)d_in[20];

  float* ws    = (float*)d_ws;
  unsigned short* emb2  = (unsigned short*)ws;                 // 16384*256 bf16 (8 MB)
  unsigned short* w2bf  = (unsigned short*)(ws + 6291456);     // 65536 us
  unsigned short* w3bf  = (unsigned short*)(ws + 6324224);     // 262144 us
  unsigned short* tebf  = (unsigned short*)(ws + 6455296);     // 196608 us
  unsigned short* Wf    = (unsigned short*)(ws + 6553600);     // 2097152 us (4 MB)
  float* cb    = ws + 7602176;                                 // 2048 f
  float* probs = ws + 8000000;                                 // 65536 f
  float* gval  = ws + 16777216;           // 16384 f
  int*   gidx  = (int*)(ws + 16793600);   // 16384 i
  float* aux   = ws + 16809984;           // 256 f
  int*   cnt   = (int*)(ws + 16810240);   // 8 i
  int*   bin   = (int*)(ws + 16810248);   // 65536 i
  unsigned short* flatbf  = (unsigned short*)(ws + 16875784);  // 8192*768 us
  unsigned short* featsbf = (unsigned short*)(ws + 20021512);  // 16384*256 us
  float* out   = (float*)d_out;

  hipMemsetAsync(aux, 0, 264 * sizeof(float), stream);   // aux(256) + cnt(8)

  patchgate_kernel<<<8192, 256, 0, stream>>>(x, gw, gb, flatbf, gidx, gval, probs);
  auxbin_kernel<<<32, 256, 0, stream>>>(probs, gidx, aux, cnt, bin);
  prep_kernel<<<640, 256, 0, stream>>>(pw2w, pw3w, tew, w2bf, w3bf, tebf,
                                       thb, resb, teb, cb);

  dim3 wg(16, 4, 8);
  wfuse_kernel<<<wg, 256, 0, stream>>>(tebf, resw, thw, Wf);

  dim3 cnng(8, 1024);
  cnn_mfma<<<cnng, 512, 0, stream>>>(flatbf, bin, cnt, dw1w, dw1b, pw1w, pw1b,
                                     dw2w, dw2b, w2bf, pw2b, dw3w, dw3b,
                                     w3bf, pw3b, featsbf);

  dim3 cg(16, 256);
  combine4<<<cg, 128, 0, stream>>>(flatbf, featsbf, Wf, cb, gval, bin, cnt, emb2);
  sum_kernel<<<256, 256, 0, stream>>>(emb2, aux, out);
}